// Round 12
// baseline (1800.980 us; speedup 1.0000x reference)
//
#include <hip/hip_runtime.h>
#include <math.h>

#define HH 7
#define WW 18
#define PP 126        // HH*WW
#define CC 16
#define NN 4096
#define EE 16384
#define BB 64
#define TILE 2016               // CC*PP, std layout
#define ZT 2880                 // 16*9*20 haloed tile (An/Ae layout)
#define WPB 12                  // waves (edges/nodes) per block
#define NTH (WPB * 64)          // 768 threads

// ---- fast transcendentals (hardware v_exp/v_log; abs err ~1e-7, thr 1.4e-3)
__device__ __forceinline__ float sp_f(float x) {
    // softplus: max(x,0) + log(1 + exp(-|x|))
    return fmaxf(x, 0.f) + __logf(1.f + __expf(-fabsf(x)));
}
__device__ __forceinline__ float elu_f(float v) {
    return v > 0.f ? v : __expf(v) - 1.f;
}
__device__ __forceinline__ float sigm_f(float x) {
    return 1.f / (1.f + __expf(-x));
}

// ---------------- weight packs -> [tap][ci][cb][4] --------------------------
// lin (32 co): q=0 filter(cb), q=1 core(cb) [row cb+16], q=2 filter(cb+8), q=3 core(cb+8)
__global__ void k_wT_lin(const float* __restrict__ w, float* __restrict__ wT) {
    int i = blockIdx.x * 256 + threadIdx.x;
    if (i < 4608) {
        int q = i & 3, cb = (i >> 2) & 7, ci = (i >> 5) & 15, tap = i >> 9;
        int co = cb + ((q >> 1) & 1) * 8 + (q & 1) * 16;
        wT[i] = w[(co * 16 + ci) * 9 + tap];
    }
}
// node/edge dual: q=0 wN(cb), q=1 wE(cb), q=2 wN(cb+8), q=3 wE(cb+8)
__global__ void k_wT_ne(const float* __restrict__ wN, const float* __restrict__ wE,
                        float* __restrict__ wT) {
    int i = blockIdx.x * 256 + threadIdx.x;
    if (i < 4608) {
        int q = i & 3, cb = (i >> 2) & 7, ci = (i >> 5) & 15, tap = i >> 9;
        int co = cb + ((q >> 1) & 1) * 8;
        const float* src = (q & 1) ? wE : wN;
        wT[i] = src[(co * 16 + ci) * 9 + tap];
    }
}

// ---------------- embedding -------------------------------------------------
__global__ __launch_bounds__(256) void k_embed(const float* __restrict__ nodes,
                                               const float* __restrict__ w,
                                               const float* __restrict__ b,
                                               float* __restrict__ atom) {
    __shared__ float tile[PP];
    __shared__ float ws[CC * 9];
    __shared__ float bs[CC];
    int n = blockIdx.x, tid = threadIdx.x;
    for (int i = tid; i < PP; i += 256) tile[i] = nodes[n * PP + i];
    for (int i = tid; i < CC * 9; i += 256) ws[i] = w[i];
    if (tid < CC) bs[tid] = b[tid];
    __syncthreads();
    for (int i = tid; i < CC * PP; i += 256) {
        int c = i / PP, p = i - c * PP, y = p / WW, x = p - (p / WW) * WW;
        float acc = bs[c];
#pragma unroll
        for (int dy = 0; dy < 3; dy++) {
            int yy = y + dy - 1; if ((unsigned)yy >= (unsigned)HH) continue;
#pragma unroll
            for (int dx = 0; dx < 3; dx++) {
                int xx = x + dx - 1; if ((unsigned)xx >= (unsigned)WW) continue;
                acc += tile[yy * WW + xx] * ws[c * 9 + dy * 3 + dx];
            }
        }
        atom[(size_t)n * CC * PP + i] = sp_f(acc);
    }
}

// ---------------- 2-co branch-free fp32 conv core ---------------------------
// zt: haloed tile [16 ci][9 rows][20 cols] in LDS, halos zero. ws: [9][16][8][4] LDS.
__device__ __forceinline__ void conv_body4(const float* zt,
                                           const float (*ws)[16][8][4],
                                           int cb, int y,
                                           float* f0, float* c0,
                                           float* f1, float* c1) {
    for (int ci = 0; ci < 16; ci++) {
        const float* zb = zt + ci * 180 + y * 20;
#pragma unroll
        for (int dy = 0; dy < 3; dy++) {
            const float* zr = zb + dy * 20;
            float4 q0 = *(const float4*)&zr[0];
            float4 q1 = *(const float4*)&zr[4];
            float4 q2 = *(const float4*)&zr[8];
            float4 q3 = *(const float4*)&zr[12];
            float4 q4 = *(const float4*)&zr[16];
            float r[20];
            r[0]=q0.x; r[1]=q0.y; r[2]=q0.z; r[3]=q0.w;
            r[4]=q1.x; r[5]=q1.y; r[6]=q1.z; r[7]=q1.w;
            r[8]=q2.x; r[9]=q2.y; r[10]=q2.z; r[11]=q2.w;
            r[12]=q3.x; r[13]=q3.y; r[14]=q3.z; r[15]=q3.w;
            r[16]=q4.x; r[17]=q4.y; r[18]=q4.z; r[19]=q4.w;
            float4 w0 = *(const float4*)&ws[dy * 3 + 0][ci][cb][0];
            float4 w1 = *(const float4*)&ws[dy * 3 + 1][ci][cb][0];
            float4 w2 = *(const float4*)&ws[dy * 3 + 2][ci][cb][0];
#pragma unroll
            for (int x = 0; x < 18; x++) {
                f0[x] = fmaf(r[x],     w0.x, f0[x]);
                c0[x] = fmaf(r[x],     w0.y, c0[x]);
                f1[x] = fmaf(r[x],     w0.z, f1[x]);
                c1[x] = fmaf(r[x],     w0.w, c1[x]);
                f0[x] = fmaf(r[x + 1], w1.x, f0[x]);
                c0[x] = fmaf(r[x + 1], w1.y, c0[x]);
                f1[x] = fmaf(r[x + 1], w1.z, f1[x]);
                c1[x] = fmaf(r[x + 1], w1.w, c1[x]);
                f0[x] = fmaf(r[x + 2], w2.x, f0[x]);
                c0[x] = fmaf(r[x + 2], w2.y, c0[x]);
                f1[x] = fmaf(r[x + 2], w2.z, f1[x]);
                c1[x] = fmaf(r[x + 2], w2.w, c1[x]);
            }
        }
    }
}

// ------------- per-node dual conv: 1 node/WAVE, 12 waves/block --------------
__global__ __launch_bounds__(NTH) void k_node_conv2(const float* __restrict__ atom,
                                                    const float* __restrict__ wT,
                                                    float* __restrict__ An,
                                                    float* __restrict__ Ae) {
    __shared__ __align__(16) float zf[WPB * ZT];      // 138240 B
    __shared__ __align__(16) float ws4[9][16][8][4];  // 18432 B
    int tid = threadIdx.x;
    for (int i = tid; i < 4608; i += NTH) ((float*)ws4)[i] = wT[i];
    __syncthreads();   // the only block barrier

    int we = tid >> 6, lane = tid & 63;
    int n = blockIdx.x * WPB + we;
    if (n >= NN) return;
    float* zw = &zf[we * ZT];
    const float* src = atom + (size_t)n * TILE;
    // wave-private halo-gather load (std -> halo layout, halos zero)
    for (int r = lane; r < ZT; r += 64) {
        int ci = r / 180, rr = r - ci * 180;
        int yy = rr / 20, xx = rr - yy * 20;
        float v = 0.f;
        if ((unsigned)(yy - 1) < 7u && (unsigned)(xx - 1) < 18u)
            v = src[ci * 126 + (yy - 1) * 18 + (xx - 1)];
        zw[r] = v;
    }
    int cb = lane & 7, y = lane >> 3;
    bool act = y < 7;
    float f0[18], c0[18], f1[18], c1[18];
#pragma unroll
    for (int x = 0; x < 18; x++) { f0[x] = 0.f; c0[x] = 0.f; f1[x] = 0.f; c1[x] = 0.f; }
    if (act) conv_body4(zw, ws4, cb, y, f0, c0, f1, c1);
    // re-stage outputs in own region (wave lockstep: conv reads done)
    for (int r = lane; r < ZT; r += 64) zw[r] = 0.f;
    int b0 = cb * 180 + (y + 1) * 20 + 1;
    int b1 = (cb + 8) * 180 + (y + 1) * 20 + 1;
    if (act) {
#pragma unroll
        for (int x = 0; x < 18; x++) { zw[b0 + x] = f0[x]; zw[b1 + x] = f1[x]; }
    }
    float4* an4 = (float4*)&An[(size_t)n * ZT];
    for (int j = lane; j < ZT / 4; j += 64) an4[j] = ((const float4*)zw)[j];
    if (act) {
#pragma unroll
        for (int x = 0; x < 18; x++) { zw[b0 + x] = c0[x]; zw[b1 + x] = c1[x]; }
    }
    float4* ae4 = (float4*)&Ae[(size_t)n * ZT];
    for (int j = lane; j < ZT / 4; j += 64) ae4[j] = ((const float4*)zw)[j];
}

// ---------------- per-edge conv: 1 edge/WAVE, 12 waves/block ----------------
__global__ __launch_bounds__(NTH) void k_edge(const float* __restrict__ An,
                                              const float* __restrict__ Ae,
                                              const int* __restrict__ es,
                                              const int* __restrict__ et,
                                              const float* __restrict__ wT,
                                              const float* __restrict__ lb,
                                              float* __restrict__ outb) {
    __shared__ __align__(16) float zf[WPB * ZT];      // 138240 B
    __shared__ __align__(16) float ws4[9][16][8][4];  // 18432 B
    int tid = threadIdx.x;
    for (int i = tid; i < 4608; i += NTH) ((float*)ws4)[i] = wT[i];
    __syncthreads();   // the only block barrier

    int we = tid >> 6, lane = tid & 63;
    int e = blockIdx.x * WPB + we;
    if (e >= EE) return;
    int s = es[e], t = et[e];
    float* zw = &zf[we * ZT];
    const float4* an4 = (const float4*)&An[(size_t)s * ZT];
    const float4* ae4 = (const float4*)&Ae[(size_t)t * ZT];
    // wave-private float4 load+elu (halos 0*0 -> elu(0)=0)
    for (int j = lane; j < ZT / 4; j += 64) {
        float4 a4 = an4[j], b4 = ae4[j];
        float4 r;
        r.x = elu_f(a4.x * b4.x);
        r.y = elu_f(a4.y * b4.y);
        r.z = elu_f(a4.z * b4.z);
        r.w = elu_f(a4.w * b4.w);
        ((float4*)zw)[j] = r;
    }
    int cb = lane & 7, y = lane >> 3;
    bool act = y < 7;
    float f0[18], c0[18], f1[18], c1[18];
#pragma unroll
    for (int x = 0; x < 18; x++) { f0[x] = 0.f; c0[x] = 0.f; f1[x] = 0.f; c1[x] = 0.f; }
    if (act) conv_body4(zw, ws4, cb, y, f0, c0, f1, c1);
    // stage msg in own region, std layout [16ch][126] (wave lockstep: conv done)
    if (act) {
        float bf0 = lb[cb], bc0 = lb[cb + 16], bf1 = lb[cb + 8], bc1 = lb[cb + 24];
        int base0 = cb * 126 + y * 18;
        int base1 = (cb + 8) * 126 + y * 18;
#pragma unroll
        for (int x = 0; x < 18; x++) {
            zw[base0 + x] = sigm_f(f0[x] + bf0) * sp_f(c0[x] + bc0);
            zw[base1 + x] = sigm_f(f1[x] + bf1) * sp_f(c1[x] + bc1);
        }
    }
    // coalesced atomic scatter (wave-private)
    float* outn = outb + (size_t)s * TILE;
    for (int j = lane; j < TILE; j += 64)
        unsafeAtomicAdd(&outn[j], zw[j]);
}

// ---------------- BN statistics (double accumulation) -----------------------
template <int C, int S>
__global__ void k_bn_stats(const float* __restrict__ X, double* __restrict__ acc, int M) {
    int c = blockIdx.y, tid = threadIdx.x;
    double s1 = 0.0, s2 = 0.0;
    for (int m = blockIdx.x; m < M; m += gridDim.x) {
        const float* xr = &X[((size_t)m * C + c) * S];
        for (int s = tid; s < S; s += blockDim.x) {
            float v = xr[s];
            s1 += v; s2 += (double)v * v;
        }
    }
    __shared__ double sh1[256], sh2[256];
    sh1[tid] = s1; sh2[tid] = s2;
    __syncthreads();
    for (int off = blockDim.x >> 1; off > 0; off >>= 1) {
        if (tid < off) { sh1[tid] += sh1[tid + off]; sh2[tid] += sh2[tid + off]; }
        __syncthreads();
    }
    if (tid == 0) {
        unsafeAtomicAdd(&acc[2 * c], sh1[0]);
        unsafeAtomicAdd(&acc[2 * c + 1], sh2[0]);
    }
}

__global__ void k_bn_fin(const double* __restrict__ acc, const float* __restrict__ g,
                         const float* __restrict__ b, double invn,
                         float* __restrict__ scl, float* __restrict__ shf) {
    int c = threadIdx.x;
    if (c < 16) {
        double m = acc[2 * c] * invn;
        double v = acc[2 * c + 1] * invn - m * m;
        double s = (double)g[c] / sqrt(v + 1e-5);
        scl[c] = (float)s;
        shf[c] = (float)((double)b[c] - s * m);
    }
}

__global__ __launch_bounds__(256) void k_bn_res(float* __restrict__ atom,
                                                const float* __restrict__ outb,
                                                const float* __restrict__ scl,
                                                const float* __restrict__ shf) {
    __shared__ float sc[16], sh[16];
    int tid = threadIdx.x;
    if (tid < 16) { sc[tid] = scl[tid]; sh[tid] = shf[tid]; }
    __syncthreads();
    const long total = (long)NN * CC * PP;
    for (long i = (long)blockIdx.x * blockDim.x + tid; i < total;
         i += (long)gridDim.x * blockDim.x) {
        int c = (int)((i / PP) & 15);
        atom[i] += sc[c] * outb[i] + sh[c];
    }
}

// ---------------- mean pooling over graphs (atomic) -------------------------
__global__ __launch_bounds__(256) void k_pool(const float* __restrict__ atom,
                                              const int* __restrict__ gi,
                                              float* __restrict__ crys) {
    int n = blockIdx.x;
    int g = gi[n];
    const float* a = &atom[(size_t)n * CC * PP];
    float* cr = &crys[(size_t)g * CC * PP];
    for (int i = threadIdx.x; i < CC * PP; i += 256) unsafeAtomicAdd(&cr[i], a[i]);
}

// ---------------- conv_to_fc ------------------------------------------------
__global__ __launch_bounds__(256) void k_ctf(const float* __restrict__ crys,
                                             const int* __restrict__ counts,
                                             const float* __restrict__ w,
                                             const float* __restrict__ b,
                                             float* __restrict__ flat) {
    __shared__ float tile[CC * PP];
    __shared__ float ws[CC * CC * 9];
    __shared__ float bs[CC];
    int g = blockIdx.x, tid = threadIdx.x;
    float cnt = (float)counts[g];
    for (int i = tid; i < CC * PP; i += 256) tile[i] = crys[(size_t)g * CC * PP + i] / cnt;
    for (int i = tid; i < CC * CC * 9; i += 256) ws[i] = w[i];
    if (tid < CC) bs[tid] = b[tid];
    __syncthreads();
    for (int i = tid; i < CC * PP; i += 256) {
        int co = i / PP, p = i - co * PP, y = p / WW, x = p - (p / WW) * WW;
        float acc = bs[co];
#pragma unroll
        for (int dy = 0; dy < 3; dy++) {
            int yy = y + dy - 1; if ((unsigned)yy >= (unsigned)HH) continue;
#pragma unroll
            for (int dx = 0; dx < 3; dx++) {
                int xx = x + dx - 1; if ((unsigned)xx >= (unsigned)WW) continue;
                int zoff = yy * WW + xx, tap = dy * 3 + dx;
                const float* tp = &tile[zoff];
                const float* wp = &ws[co * 144 + tap];
#pragma unroll
                for (int ci = 0; ci < CC; ci++) acc += tp[ci * PP] * wp[ci * 9];
            }
        }
        flat[(size_t)g * CC * PP + i] = sp_f(acc);
    }
}

// ---------------- space branch ----------------------------------------------
__global__ __launch_bounds__(256) void k_space1(const int* __restrict__ nsites,
                                                const int* __restrict__ sgs,
                                                const float* __restrict__ w1,
                                                const float* __restrict__ b1,
                                                const float* __restrict__ w2,
                                                const float* __restrict__ b2,
                                                const float* __restrict__ cw,
                                                const float* __restrict__ cb,
                                                float* __restrict__ sembp) {
    __shared__ float outer[256];
    __shared__ float row[16], col[16];
    __shared__ float cws[144], cbs[16];
    int g = blockIdx.x, tid = threadIdx.x;
    if (tid < 16) {
        float ns = (float)nsites[g], sg = (float)sgs[g];
        row[tid] = ns * w1[2 * tid] + sg * w1[2 * tid + 1] + b1[tid];
        col[tid] = ns * w2[2 * tid] + sg * w2[2 * tid + 1] + b2[tid];
        cbs[tid] = cb[tid];
    }
    if (tid >= 64 && tid < 64 + 144) cws[tid - 64] = cw[tid - 64];
    __syncthreads();
    outer[tid] = row[tid >> 4] * col[tid & 15];
    __syncthreads();
    for (int i = tid; i < 16 * 256; i += 256) {
        int c = i >> 8, p = i & 255, y = p >> 4, x = p & 15;
        float acc = cbs[c];
#pragma unroll
        for (int dy = 0; dy < 3; dy++) {
            int yy = y + dy - 1; if ((unsigned)yy >= 16u) continue;
#pragma unroll
            for (int dx = 0; dx < 3; dx++) {
                int xx = x + dx - 1; if ((unsigned)xx >= 16u) continue;
                acc += outer[yy * 16 + xx] * cws[c * 9 + dy * 3 + dx];
            }
        }
        sembp[(size_t)g * 4096 + i] = acc;
    }
}

__global__ __launch_bounds__(256) void k_bn_sp256(const float* __restrict__ X,
                                                  float* __restrict__ Y,
                                                  const float* __restrict__ scl,
                                                  const float* __restrict__ shf) {
    __shared__ float sc[16], sh[16];
    if (threadIdx.x < 16) { sc[threadIdx.x] = scl[threadIdx.x]; sh[threadIdx.x] = shf[threadIdx.x]; }
    __syncthreads();
    int total = BB * 16 * 256;
    for (int i = blockIdx.x * blockDim.x + threadIdx.x; i < total;
         i += gridDim.x * blockDim.x) {
        int c = (i >> 8) & 15;
        Y[i] = sp_f(sc[c] * X[i] + sh[c]);
    }
}

__global__ __launch_bounds__(256) void k_space_conv(const float* __restrict__ X,
                                                    const float* __restrict__ w,
                                                    const float* __restrict__ b,
                                                    float* __restrict__ Y) {
    __shared__ float tile[16 * 256];
    __shared__ float ws[2304], bs[16];
    int g = blockIdx.x, tid = threadIdx.x;
    for (int i = tid; i < 4096; i += 256) tile[i] = X[(size_t)g * 4096 + i];
    for (int i = tid; i < 2304; i += 256) ws[i] = w[i];
    if (tid < 16) bs[tid] = b[tid];
    __syncthreads();
    for (int i = tid; i < 4096; i += 256) {
        int c = i >> 8, p = i & 255, y = p >> 4, x = p & 15;
        float acc = bs[c];
#pragma unroll
        for (int dy = 0; dy < 3; dy++) {
            int yy = y + dy - 1; if ((unsigned)yy >= 16u) continue;
#pragma unroll
            for (int dx = 0; dx < 3; dx++) {
                int xx = x + dx - 1; if ((unsigned)xx >= 16u) continue;
                int tap = dy * 3 + dx;
                const float* wp = &ws[c * 144 + tap];
                const float* tp = &tile[yy * 16 + xx];
#pragma unroll
                for (int ci = 0; ci < 16; ci++) acc += tp[ci * 256] * wp[ci * 9];
            }
        }
        Y[(size_t)g * 4096 + i] = acc;
    }
}

__global__ __launch_bounds__(256) void k_space_tail(const float* __restrict__ ypre,
                                                    const float* __restrict__ scl,
                                                    const float* __restrict__ shf,
                                                    const float* __restrict__ fc3w,
                                                    const float* __restrict__ fc3b,
                                                    float* __restrict__ sout) {
    __shared__ float red[256];
    int g = blockIdx.x, tid = threadIdx.x;
    float val = 0.f;
    if (tid < 144) {
        int c = tid / 9, cell = tid - c * 9, py = cell / 3, px = cell - py * 3;
        float sc = scl[c], sh = shf[c];
        float mx = -INFINITY;
        const float* base = &ypre[((size_t)g * 16 + c) * 256];
        for (int yy = py * 5; yy < py * 5 + 5; yy++)
            for (int xx = px * 5; xx < px * 5 + 5; xx++)
                mx = fmaxf(mx, sc * base[yy * 16 + xx] + sh);
        val = sp_f(mx) * fc3w[tid];
    }
    red[tid] = val;
    __syncthreads();
    for (int off = 128; off > 0; off >>= 1) {
        if (tid < off) red[tid] += red[tid + off];
        __syncthreads();
    }
    if (tid == 0) sout[g] = red[0] + fc3b[0];
}

// ---------------- FC head ---------------------------------------------------
__global__ __launch_bounds__(256) void k_head(const float* __restrict__ flat,
                                              const float* __restrict__ fc1w,
                                              const float* __restrict__ fc1b,
                                              const float* __restrict__ fc2w,
                                              const float* __restrict__ fc2b,
                                              const float* __restrict__ regw,
                                              const float* __restrict__ regb,
                                              const float* __restrict__ sout,
                                              const float* __restrict__ eps,
                                              float* __restrict__ out) {
    int g = blockIdx.x, tid = threadIdx.x;
    __shared__ float h1[32], h2[32];
    int o = tid >> 3, r = tid & 7;
    float part = 0.f;
    const float* fr = &flat[(size_t)g * 2016];
    const float* wr = &fc1w[(size_t)o * 2016];
    for (int j = r; j < 2016; j += 8) part += fr[j] * wr[j];
    part += __shfl_down(part, 4, 8);
    part += __shfl_down(part, 2, 8);
    part += __shfl_down(part, 1, 8);
    if (r == 0) h1[o] = sp_f(part + fc1b[o]);
    __syncthreads();
    if (tid < 32) {
        float a = fc2b[tid];
        for (int j = 0; j < 32; j++) a += h1[j] * fc2w[tid * 32 + j];
        h2[tid] = sp_f(a);
    }
    __syncthreads();
    if (tid == 0) {
        float a = regb[0];
        for (int j = 0; j < 32; j++) a += h2[j] * regw[j];
        out[g] = a + eps[0] * sout[g];
    }
}

// ===========================================================================
extern "C" void kernel_launch(void* const* d_in, const int* in_sizes, int n_in,
                              void* d_out, int out_size, void* d_ws, size_t ws_size,
                              hipStream_t stream) {
    const float* nodes   = (const float*)d_in[0];
    const int*   es      = (const int*)d_in[1];
    const int*   et      = (const int*)d_in[2];
    const int*   gi      = (const int*)d_in[3];
    const int*   cnt     = (const int*)d_in[4];
    const int*   nsites  = (const int*)d_in[5];
    const int*   sgs     = (const int*)d_in[6];
    const float* emb_w   = (const float*)d_in[7];
    const float* emb_b   = (const float*)d_in[8];
    const float* cl_nw   = (const float*)d_in[9];
    const float* cl_ew   = (const float*)d_in[10];
    const float* cl_lw   = (const float*)d_in[11];
    const float* cl_lb   = (const float*)d_in[12];
    const float* cl_bg   = (const float*)d_in[13];
    const float* cl_bb   = (const float*)d_in[14];
    const float* se_w1   = (const float*)d_in[15];
    const float* se_b1   = (const float*)d_in[16];
    const float* se_w2   = (const float*)d_in[17];
    const float* se_b2   = (const float*)d_in[18];
    const float* se_cw   = (const float*)d_in[19];
    const float* se_cb   = (const float*)d_in[20];
    const float* se_bg   = (const float*)d_in[21];
    const float* se_bb   = (const float*)d_in[22];
    const float* sf_cw   = (const float*)d_in[23];
    const float* sf_cb   = (const float*)d_in[24];
    const float* sf_bg   = (const float*)d_in[25];
    const float* sf_bb   = (const float*)d_in[26];
    const float* ctf_w   = (const float*)d_in[27];
    const float* ctf_b   = (const float*)d_in[28];
    const float* fc1_w   = (const float*)d_in[29];
    const float* fc1_b   = (const float*)d_in[30];
    const float* fc2_w   = (const float*)d_in[31];
    const float* fc2_b   = (const float*)d_in[32];
    const float* reg_w   = (const float*)d_in[33];
    const float* reg_b   = (const float*)d_in[34];
    const float* fc3_w   = (const float*)d_in[35];
    const float* fc3_b   = (const float*)d_in[36];
    const float* eps     = (const float*)d_in[37];
    float* out = (float*)d_out;

    const size_t ATOM_B = (size_t)NN * TILE * sizeof(float);   // 33 MB
    const size_t HALO_B = (size_t)NN * ZT * sizeof(float);     // 47.2 MB
    char* ws = (char*)d_ws;
    float*  atom  = (float*)ws;              ws += ATOM_B;
    float*  An    = (float*)ws;              ws += HALO_B;
    float*  Ae    = (float*)ws;              ws += HALO_B;
    float*  outb  = (float*)ws;              ws += ATOM_B;
    double* acc   = (double*)ws;             ws += 256;
    float*  scl   = (float*)ws;              ws += 256;
    float*  shf   = (float*)ws;              ws += 256;
    float*  sout  = (float*)ws;              ws += 256;
    float*  nwT   = (float*)ws;              ws += 4608 * sizeof(float);
    float*  lwT   = (float*)ws;              ws += 4608 * sizeof(float);
    float*  crys  = (float*)ws;              ws += (size_t)BB * TILE * sizeof(float);
    float*  flat  = (float*)ws;              ws += (size_t)BB * TILE * sizeof(float);
    float*  sembp = (float*)ws;              ws += (size_t)BB * 16 * 256 * sizeof(float);
    float*  semb  = (float*)ws;              ws += (size_t)BB * 16 * 256 * sizeof(float);
    float*  ypre  = (float*)ws;              ws += (size_t)BB * 16 * 256 * sizeof(float);

    // ---- embedding
    k_embed<<<NN, 256, 0, stream>>>(nodes, emb_w, emb_b, atom);

    // ---- 3 conv layers (fp32 production path)
    for (int l = 0; l < 3; l++) {
        const float* nw = cl_nw + (size_t)l * CC * CC * 9;
        const float* ew = cl_ew + (size_t)l * CC * CC * 9;
        const float* lw = cl_lw + (size_t)l * 32 * CC * 9;
        const float* lb = cl_lb + (size_t)l * 32;
        const float* bg = cl_bg + (size_t)l * 16;
        const float* bb = cl_bb + (size_t)l * 16;

        k_wT_ne<<<18, 256, 0, stream>>>(nw, ew, nwT);
        k_wT_lin<<<18, 256, 0, stream>>>(lw, lwT);
        k_node_conv2<<<(NN + WPB - 1) / WPB, NTH, 0, stream>>>(atom, nwT, An, Ae);
        hipMemcpyAsync(outb, atom, ATOM_B, hipMemcpyDeviceToDevice, stream);
        k_edge<<<(EE + WPB - 1) / WPB, NTH, 0, stream>>>(An, Ae, es, et, lwT, lb, outb);
        hipMemsetAsync(acc, 0, 16 * 2 * sizeof(double), stream);
        k_bn_stats<16, 126><<<dim3(64, 16), 128, 0, stream>>>(outb, acc, NN);
        k_bn_fin<<<1, 16, 0, stream>>>(acc, bg, bb, 1.0 / ((double)NN * PP), scl, shf);
        k_bn_res<<<2048, 256, 0, stream>>>(atom, outb, scl, shf);
    }

    // ---- space branch
    k_space1<<<BB, 256, 0, stream>>>(nsites, sgs, se_w1, se_b1, se_w2, se_b2,
                                     se_cw, se_cb, sembp);
    hipMemsetAsync(acc, 0, 16 * 2 * sizeof(double), stream);
    k_bn_stats<16, 256><<<dim3(8, 16), 256, 0, stream>>>(sembp, acc, BB);
    k_bn_fin<<<1, 16, 0, stream>>>(acc, se_bg, se_bb, 1.0 / (BB * 256.0), scl, shf);
    k_bn_sp256<<<256, 256, 0, stream>>>(sembp, semb, scl, shf);
    k_space_conv<<<BB, 256, 0, stream>>>(semb, sf_cw, sf_cb, ypre);
    hipMemsetAsync(acc, 0, 16 * 2 * sizeof(double), stream);
    k_bn_stats<16, 256><<<dim3(8, 16), 256, 0, stream>>>(ypre, acc, BB);
    k_bn_fin<<<1, 16, 0, stream>>>(acc, sf_bg, sf_bb, 1.0 / (BB * 256.0), scl, shf);
    k_space_tail<<<BB, 256, 0, stream>>>(ypre, scl, shf, fc3_w, fc3_b, sout);

    // ---- pooling + conv_to_fc + head
    hipMemsetAsync(crys, 0, (size_t)BB * TILE * sizeof(float), stream);
    k_pool<<<NN, 256, 0, stream>>>(atom, gi, crys);
    k_ctf<<<BB, 256, 0, stream>>>(crys, cnt, ctf_w, ctf_b, flat);
    k_head<<<BB, 256, 0, stream>>>(flat, fc1_w, fc1_b, fc2_w, fc2_b,
                                   reg_w, reg_b, sout, eps, out);
}

// Round 13
// 1536.881 us; speedup vs baseline: 1.1718x; 1.1718x over previous
//
#include <hip/hip_runtime.h>
#include <math.h>

#define HH 7
#define WW 18
#define PP 126        // HH*WW
#define CC 16
#define NN 4096
#define EE 16384
#define BB 64
#define TILE 2016               // CC*PP, std layout
#define ZT 2880                 // 16*9*20 haloed tile (An/Ae global layout)
#define ZTH 1440                // half tile: 8 ci * 9 rows * 20 cols

// ---- fast transcendentals (hardware v_exp/v_log; abs err ~1e-7, thr 1.4e-3)
__device__ __forceinline__ float sp_f(float x) {
    // softplus: max(x,0) + log(1 + exp(-|x|))
    return fmaxf(x, 0.f) + __logf(1.f + __expf(-fabsf(x)));
}
__device__ __forceinline__ float elu_f(float v) {
    return v > 0.f ? v : __expf(v) - 1.f;
}
__device__ __forceinline__ float sigm_f(float x) {
    return 1.f / (1.f + __expf(-x));
}

// ---------------- weight packs -> [tap][ci][cb][4] --------------------------
// lin (32 co): q=0 filter(cb), q=1 core(cb) [row cb+16], q=2 filter(cb+8), q=3 core(cb+8)
__global__ void k_wT_lin(const float* __restrict__ w, float* __restrict__ wT) {
    int i = blockIdx.x * 256 + threadIdx.x;
    if (i < 4608) {
        int q = i & 3, cb = (i >> 2) & 7, ci = (i >> 5) & 15, tap = i >> 9;
        int co = cb + ((q >> 1) & 1) * 8 + (q & 1) * 16;
        wT[i] = w[(co * 16 + ci) * 9 + tap];
    }
}
// node/edge dual: q=0 wN(cb), q=1 wE(cb), q=2 wN(cb+8), q=3 wE(cb+8)
__global__ void k_wT_ne(const float* __restrict__ wN, const float* __restrict__ wE,
                        float* __restrict__ wT) {
    int i = blockIdx.x * 256 + threadIdx.x;
    if (i < 4608) {
        int q = i & 3, cb = (i >> 2) & 7, ci = (i >> 5) & 15, tap = i >> 9;
        int co = cb + ((q >> 1) & 1) * 8;
        const float* src = (q & 1) ? wE : wN;
        wT[i] = src[(co * 16 + ci) * 9 + tap];
    }
}

// ---------------- embedding -------------------------------------------------
__global__ __launch_bounds__(256) void k_embed(const float* __restrict__ nodes,
                                               const float* __restrict__ w,
                                               const float* __restrict__ b,
                                               float* __restrict__ atom) {
    __shared__ float tile[PP];
    __shared__ float ws[CC * 9];
    __shared__ float bs[CC];
    int n = blockIdx.x, tid = threadIdx.x;
    for (int i = tid; i < PP; i += 256) tile[i] = nodes[n * PP + i];
    for (int i = tid; i < CC * 9; i += 256) ws[i] = w[i];
    if (tid < CC) bs[tid] = b[tid];
    __syncthreads();
    for (int i = tid; i < CC * PP; i += 256) {
        int c = i / PP, p = i - c * PP, y = p / WW, x = p - (p / WW) * WW;
        float acc = bs[c];
#pragma unroll
        for (int dy = 0; dy < 3; dy++) {
            int yy = y + dy - 1; if ((unsigned)yy >= (unsigned)HH) continue;
#pragma unroll
            for (int dx = 0; dx < 3; dx++) {
                int xx = x + dx - 1; if ((unsigned)xx >= (unsigned)WW) continue;
                acc += tile[yy * WW + xx] * ws[c * 9 + dy * 3 + dx];
            }
        }
        atom[(size_t)n * CC * PP + i] = sp_f(acc);
    }
}

// ---------------- 2-co conv core over an 8-ci HALF tile ---------------------
// zt: haloed half tile [8 ci][9 rows][20 cols] in LDS, halos zero.
// ws: full [9][16][8][4] LDS; cih = 0 or 8 selects the ci half.
__device__ __forceinline__ void conv_body4h(const float* zt,
                                            const float (*ws)[16][8][4],
                                            int cih, int cb, int y,
                                            float* f0, float* c0,
                                            float* f1, float* c1) {
    for (int ci = 0; ci < 8; ci++) {
        const float* zb = zt + ci * 180 + y * 20;
#pragma unroll
        for (int dy = 0; dy < 3; dy++) {
            const float* zr = zb + dy * 20;
            float4 q0 = *(const float4*)&zr[0];
            float4 q1 = *(const float4*)&zr[4];
            float4 q2 = *(const float4*)&zr[8];
            float4 q3 = *(const float4*)&zr[12];
            float4 q4 = *(const float4*)&zr[16];
            float r[20];
            r[0]=q0.x; r[1]=q0.y; r[2]=q0.z; r[3]=q0.w;
            r[4]=q1.x; r[5]=q1.y; r[6]=q1.z; r[7]=q1.w;
            r[8]=q2.x; r[9]=q2.y; r[10]=q2.z; r[11]=q2.w;
            r[12]=q3.x; r[13]=q3.y; r[14]=q3.z; r[15]=q3.w;
            r[16]=q4.x; r[17]=q4.y; r[18]=q4.z; r[19]=q4.w;
            float4 w0 = *(const float4*)&ws[dy * 3 + 0][cih + ci][cb][0];
            float4 w1 = *(const float4*)&ws[dy * 3 + 1][cih + ci][cb][0];
            float4 w2 = *(const float4*)&ws[dy * 3 + 2][cih + ci][cb][0];
#pragma unroll
            for (int x = 0; x < 18; x++) {
                f0[x] = fmaf(r[x],     w0.x, f0[x]);
                c0[x] = fmaf(r[x],     w0.y, c0[x]);
                f1[x] = fmaf(r[x],     w0.z, f1[x]);
                c1[x] = fmaf(r[x],     w0.w, c1[x]);
                f0[x] = fmaf(r[x + 1], w1.x, f0[x]);
                c0[x] = fmaf(r[x + 1], w1.y, c0[x]);
                f1[x] = fmaf(r[x + 1], w1.z, f1[x]);
                c1[x] = fmaf(r[x + 1], w1.w, c1[x]);
                f0[x] = fmaf(r[x + 2], w2.x, f0[x]);
                c0[x] = fmaf(r[x + 2], w2.y, c0[x]);
                f1[x] = fmaf(r[x + 2], w2.z, f1[x]);
                c1[x] = fmaf(r[x + 2], w2.w, c1[x]);
            }
        }
    }
}

// ------------- per-node dual conv: 1 node/WAVE, ci-halved tile --------------
__global__ __launch_bounds__(256) void k_node_conv2(const float* __restrict__ atom,
                                                    const float* __restrict__ wT,
                                                    float* __restrict__ An,
                                                    float* __restrict__ Ae) {
    __shared__ __align__(16) float zf[4 * ZTH];       // 23040 B
    __shared__ __align__(16) float ws4[9][16][8][4];  // 18432 B
    int tid = threadIdx.x;
    for (int i = tid; i < 4608; i += 256) ((float*)ws4)[i] = wT[i];
    __syncthreads();   // the only block barrier

    int we = tid >> 6, lane = tid & 63;
    int n = blockIdx.x * 4 + we;
    float* zw = &zf[we * ZTH];
    const float* src = atom + (size_t)n * TILE;
    int cb = lane & 7, y = lane >> 3;
    bool act = y < 7;
    float f0[18], c0[18], f1[18], c1[18];
#pragma unroll
    for (int x = 0; x < 18; x++) { f0[x] = 0.f; c0[x] = 0.f; f1[x] = 0.f; c1[x] = 0.f; }
#pragma unroll
    for (int h = 0; h < 2; h++) {
        // wave-private halo-gather load of ci half (std -> halo layout, halos zero)
        for (int r = lane; r < ZTH; r += 64) {
            int ci = r / 180, rr = r - ci * 180;
            int yy = rr / 20, xx = rr - yy * 20;
            float v = 0.f;
            if ((unsigned)(yy - 1) < 7u && (unsigned)(xx - 1) < 18u)
                v = src[(ci + 8 * h) * 126 + (yy - 1) * 18 + (xx - 1)];
            zw[r] = v;
        }
        if (act) conv_body4h(zw, ws4, 8 * h, cb, y, f0, c0, f1, c1);
    }
    // store in 4 half-chunks: An(co 0..7 = f0), An(co 8..15 = f1), Ae(c0), Ae(c1)
    for (int r = lane; r < ZTH; r += 64) zw[r] = 0.f;
    int b0 = cb * 180 + (y + 1) * 20 + 1;
    float4* an4 = (float4*)&An[(size_t)n * ZT];
    float4* ae4 = (float4*)&Ae[(size_t)n * ZT];
    if (act) {
#pragma unroll
        for (int x = 0; x < 18; x++) zw[b0 + x] = f0[x];
    }
    for (int j = lane; j < ZTH / 4; j += 64) an4[j] = ((const float4*)zw)[j];
    if (act) {
#pragma unroll
        for (int x = 0; x < 18; x++) zw[b0 + x] = f1[x];
    }
    for (int j = lane; j < ZTH / 4; j += 64) an4[ZTH / 4 + j] = ((const float4*)zw)[j];
    if (act) {
#pragma unroll
        for (int x = 0; x < 18; x++) zw[b0 + x] = c0[x];
    }
    for (int j = lane; j < ZTH / 4; j += 64) ae4[j] = ((const float4*)zw)[j];
    if (act) {
#pragma unroll
        for (int x = 0; x < 18; x++) zw[b0 + x] = c1[x];
    }
    for (int j = lane; j < ZTH / 4; j += 64) ae4[ZTH / 4 + j] = ((const float4*)zw)[j];
}

// ---------------- per-edge conv: 1 edge/WAVE, ci-halved tile ----------------
__global__ __launch_bounds__(256) void k_edge(const float* __restrict__ An,
                                              const float* __restrict__ Ae,
                                              const int* __restrict__ es,
                                              const int* __restrict__ et,
                                              const float* __restrict__ wT,
                                              const float* __restrict__ lb,
                                              float* __restrict__ outb) {
    __shared__ __align__(16) float zf[4 * ZTH];       // 23040 B
    __shared__ __align__(16) float ws4[9][16][8][4];  // 18432 B
    int tid = threadIdx.x;
    for (int i = tid; i < 4608; i += 256) ((float*)ws4)[i] = wT[i];
    __syncthreads();   // the only block barrier

    int we = tid >> 6, lane = tid & 63;
    int e = blockIdx.x * 4 + we;
    int s = es[e], t = et[e];
    float* zw = &zf[we * ZTH];
    int cb = lane & 7, y = lane >> 3;
    bool act = y < 7;
    float f0[18], c0[18], f1[18], c1[18];
#pragma unroll
    for (int x = 0; x < 18; x++) { f0[x] = 0.f; c0[x] = 0.f; f1[x] = 0.f; c1[x] = 0.f; }
#pragma unroll
    for (int h = 0; h < 2; h++) {
        const float4* an4 = (const float4*)&An[(size_t)s * ZT + h * ZTH];
        const float4* ae4 = (const float4*)&Ae[(size_t)t * ZT + h * ZTH];
        // wave-private float4 load+elu (halos 0*0 -> elu(0)=0)
        for (int j = lane; j < ZTH / 4; j += 64) {
            float4 a4 = an4[j], b4 = ae4[j];
            float4 r;
            r.x = elu_f(a4.x * b4.x);
            r.y = elu_f(a4.y * b4.y);
            r.z = elu_f(a4.z * b4.z);
            r.w = elu_f(a4.w * b4.w);
            ((float4*)zw)[j] = r;
        }
        if (act) conv_body4h(zw, ws4, 8 * h, cb, y, f0, c0, f1, c1);
    }
    // epilogue + scatter in two 1008-float chunks (channels 0..7, then 8..15)
    float* outn = outb + (size_t)s * TILE;
    int base = cb * 126 + y * 18;
    if (act) {
        float bf0 = lb[cb], bc0 = lb[cb + 16];
#pragma unroll
        for (int x = 0; x < 18; x++)
            zw[base + x] = sigm_f(f0[x] + bf0) * sp_f(c0[x] + bc0);
    }
    for (int j = lane; j < 1008; j += 64)
        unsafeAtomicAdd(&outn[j], zw[j]);
    if (act) {
        float bf1 = lb[cb + 8], bc1 = lb[cb + 24];
#pragma unroll
        for (int x = 0; x < 18; x++)
            zw[base + x] = sigm_f(f1[x] + bf1) * sp_f(c1[x] + bc1);
    }
    for (int j = lane; j < 1008; j += 64)
        unsafeAtomicAdd(&outn[1008 + j], zw[j]);
}

// ---------------- BN statistics (double accumulation) -----------------------
template <int C, int S>
__global__ void k_bn_stats(const float* __restrict__ X, double* __restrict__ acc, int M) {
    int c = blockIdx.y, tid = threadIdx.x;
    double s1 = 0.0, s2 = 0.0;
    for (int m = blockIdx.x; m < M; m += gridDim.x) {
        const float* xr = &X[((size_t)m * C + c) * S];
        for (int s = tid; s < S; s += blockDim.x) {
            float v = xr[s];
            s1 += v; s2 += (double)v * v;
        }
    }
    __shared__ double sh1[256], sh2[256];
    sh1[tid] = s1; sh2[tid] = s2;
    __syncthreads();
    for (int off = blockDim.x >> 1; off > 0; off >>= 1) {
        if (tid < off) { sh1[tid] += sh1[tid + off]; sh2[tid] += sh2[tid + off]; }
        __syncthreads();
    }
    if (tid == 0) {
        unsafeAtomicAdd(&acc[2 * c], sh1[0]);
        unsafeAtomicAdd(&acc[2 * c + 1], sh2[0]);
    }
}

__global__ void k_bn_fin(const double* __restrict__ acc, const float* __restrict__ g,
                         const float* __restrict__ b, double invn,
                         float* __restrict__ scl, float* __restrict__ shf) {
    int c = threadIdx.x;
    if (c < 16) {
        double m = acc[2 * c] * invn;
        double v = acc[2 * c + 1] * invn - m * m;
        double s = (double)g[c] / sqrt(v + 1e-5);
        scl[c] = (float)s;
        shf[c] = (float)((double)b[c] - s * m);
    }
}

__global__ __launch_bounds__(256) void k_bn_res(float* __restrict__ atom,
                                                const float* __restrict__ outb,
                                                const float* __restrict__ scl,
                                                const float* __restrict__ shf) {
    __shared__ float sc[16], sh[16];
    int tid = threadIdx.x;
    if (tid < 16) { sc[tid] = scl[tid]; sh[tid] = shf[tid]; }
    __syncthreads();
    const long total = (long)NN * CC * PP;
    for (long i = (long)blockIdx.x * blockDim.x + tid; i < total;
         i += (long)gridDim.x * blockDim.x) {
        int c = (int)((i / PP) & 15);
        atom[i] += sc[c] * outb[i] + sh[c];
    }
}

// ---------------- mean pooling over graphs (atomic) -------------------------
__global__ __launch_bounds__(256) void k_pool(const float* __restrict__ atom,
                                              const int* __restrict__ gi,
                                              float* __restrict__ crys) {
    int n = blockIdx.x;
    int g = gi[n];
    const float* a = &atom[(size_t)n * CC * PP];
    float* cr = &crys[(size_t)g * CC * PP];
    for (int i = threadIdx.x; i < CC * PP; i += 256) unsafeAtomicAdd(&cr[i], a[i]);
}

// ---------------- conv_to_fc ------------------------------------------------
__global__ __launch_bounds__(256) void k_ctf(const float* __restrict__ crys,
                                             const int* __restrict__ counts,
                                             const float* __restrict__ w,
                                             const float* __restrict__ b,
                                             float* __restrict__ flat) {
    __shared__ float tile[CC * PP];
    __shared__ float ws[CC * CC * 9];
    __shared__ float bs[CC];
    int g = blockIdx.x, tid = threadIdx.x;
    float cnt = (float)counts[g];
    for (int i = tid; i < CC * PP; i += 256) tile[i] = crys[(size_t)g * CC * PP + i] / cnt;
    for (int i = tid; i < CC * CC * 9; i += 256) ws[i] = w[i];
    if (tid < CC) bs[tid] = b[tid];
    __syncthreads();
    for (int i = tid; i < CC * PP; i += 256) {
        int co = i / PP, p = i - co * PP, y = p / WW, x = p - (p / WW) * WW;
        float acc = bs[co];
#pragma unroll
        for (int dy = 0; dy < 3; dy++) {
            int yy = y + dy - 1; if ((unsigned)yy >= (unsigned)HH) continue;
#pragma unroll
            for (int dx = 0; dx < 3; dx++) {
                int xx = x + dx - 1; if ((unsigned)xx >= (unsigned)WW) continue;
                int zoff = yy * WW + xx, tap = dy * 3 + dx;
                const float* tp = &tile[zoff];
                const float* wp = &ws[co * 144 + tap];
#pragma unroll
                for (int ci = 0; ci < CC; ci++) acc += tp[ci * PP] * wp[ci * 9];
            }
        }
        flat[(size_t)g * CC * PP + i] = sp_f(acc);
    }
}

// ---------------- space branch ----------------------------------------------
__global__ __launch_bounds__(256) void k_space1(const int* __restrict__ nsites,
                                                const int* __restrict__ sgs,
                                                const float* __restrict__ w1,
                                                const float* __restrict__ b1,
                                                const float* __restrict__ w2,
                                                const float* __restrict__ b2,
                                                const float* __restrict__ cw,
                                                const float* __restrict__ cb,
                                                float* __restrict__ sembp) {
    __shared__ float outer[256];
    __shared__ float row[16], col[16];
    __shared__ float cws[144], cbs[16];
    int g = blockIdx.x, tid = threadIdx.x;
    if (tid < 16) {
        float ns = (float)nsites[g], sg = (float)sgs[g];
        row[tid] = ns * w1[2 * tid] + sg * w1[2 * tid + 1] + b1[tid];
        col[tid] = ns * w2[2 * tid] + sg * w2[2 * tid + 1] + b2[tid];
        cbs[tid] = cb[tid];
    }
    if (tid >= 64 && tid < 64 + 144) cws[tid - 64] = cw[tid - 64];
    __syncthreads();
    outer[tid] = row[tid >> 4] * col[tid & 15];
    __syncthreads();
    for (int i = tid; i < 16 * 256; i += 256) {
        int c = i >> 8, p = i & 255, y = p >> 4, x = p & 15;
        float acc = cbs[c];
#pragma unroll
        for (int dy = 0; dy < 3; dy++) {
            int yy = y + dy - 1; if ((unsigned)yy >= 16u) continue;
#pragma unroll
            for (int dx = 0; dx < 3; dx++) {
                int xx = x + dx - 1; if ((unsigned)xx >= 16u) continue;
                acc += outer[yy * 16 + xx] * cws[c * 9 + dy * 3 + dx];
            }
        }
        sembp[(size_t)g * 4096 + i] = acc;
    }
}

__global__ __launch_bounds__(256) void k_bn_sp256(const float* __restrict__ X,
                                                  float* __restrict__ Y,
                                                  const float* __restrict__ scl,
                                                  const float* __restrict__ shf) {
    __shared__ float sc[16], sh[16];
    if (threadIdx.x < 16) { sc[threadIdx.x] = scl[threadIdx.x]; sh[threadIdx.x] = shf[threadIdx.x]; }
    __syncthreads();
    int total = BB * 16 * 256;
    for (int i = blockIdx.x * blockDim.x + threadIdx.x; i < total;
         i += gridDim.x * blockDim.x) {
        int c = (i >> 8) & 15;
        Y[i] = sp_f(sc[c] * X[i] + sh[c]);
    }
}

__global__ __launch_bounds__(256) void k_space_conv(const float* __restrict__ X,
                                                    const float* __restrict__ w,
                                                    const float* __restrict__ b,
                                                    float* __restrict__ Y) {
    __shared__ float tile[16 * 256];
    __shared__ float ws[2304], bs[16];
    int g = blockIdx.x, tid = threadIdx.x;
    for (int i = tid; i < 4096; i += 256) tile[i] = X[(size_t)g * 4096 + i];
    for (int i = tid; i < 2304; i += 256) ws[i] = w[i];
    if (tid < 16) bs[tid] = b[tid];
    __syncthreads();
    for (int i = tid; i < 4096; i += 256) {
        int c = i >> 8, p = i & 255, y = p >> 4, x = p & 15;
        float acc = bs[c];
#pragma unroll
        for (int dy = 0; dy < 3; dy++) {
            int yy = y + dy - 1; if ((unsigned)yy >= 16u) continue;
#pragma unroll
            for (int dx = 0; dx < 3; dx++) {
                int xx = x + dx - 1; if ((unsigned)xx >= 16u) continue;
                int tap = dy * 3 + dx;
                const float* wp = &ws[c * 144 + tap];
                const float* tp = &tile[yy * 16 + xx];
#pragma unroll
                for (int ci = 0; ci < 16; ci++) acc += tp[ci * 256] * wp[ci * 9];
            }
        }
        Y[(size_t)g * 4096 + i] = acc;
    }
}

__global__ __launch_bounds__(256) void k_space_tail(const float* __restrict__ ypre,
                                                    const float* __restrict__ scl,
                                                    const float* __restrict__ shf,
                                                    const float* __restrict__ fc3w,
                                                    const float* __restrict__ fc3b,
                                                    float* __restrict__ sout) {
    __shared__ float red[256];
    int g = blockIdx.x, tid = threadIdx.x;
    float val = 0.f;
    if (tid < 144) {
        int c = tid / 9, cell = tid - c * 9, py = cell / 3, px = cell - py * 3;
        float sc = scl[c], sh = shf[c];
        float mx = -INFINITY;
        const float* base = &ypre[((size_t)g * 16 + c) * 256];
        for (int yy = py * 5; yy < py * 5 + 5; yy++)
            for (int xx = px * 5; xx < px * 5 + 5; xx++)
                mx = fmaxf(mx, sc * base[yy * 16 + xx] + sh);
        val = sp_f(mx) * fc3w[tid];
    }
    red[tid] = val;
    __syncthreads();
    for (int off = 128; off > 0; off >>= 1) {
        if (tid < off) red[tid] += red[tid + off];
        __syncthreads();
    }
    if (tid == 0) sout[g] = red[0] + fc3b[0];
}

// ---------------- FC head ---------------------------------------------------
__global__ __launch_bounds__(256) void k_head(const float* __restrict__ flat,
                                              const float* __restrict__ fc1w,
                                              const float* __restrict__ fc1b,
                                              const float* __restrict__ fc2w,
                                              const float* __restrict__ fc2b,
                                              const float* __restrict__ regw,
                                              const float* __restrict__ regb,
                                              const float* __restrict__ sout,
                                              const float* __restrict__ eps,
                                              float* __restrict__ out) {
    int g = blockIdx.x, tid = threadIdx.x;
    __shared__ float h1[32], h2[32];
    int o = tid >> 3, r = tid & 7;
    float part = 0.f;
    const float* fr = &flat[(size_t)g * 2016];
    const float* wr = &fc1w[(size_t)o * 2016];
    for (int j = r; j < 2016; j += 8) part += fr[j] * wr[j];
    part += __shfl_down(part, 4, 8);
    part += __shfl_down(part, 2, 8);
    part += __shfl_down(part, 1, 8);
    if (r == 0) h1[o] = sp_f(part + fc1b[o]);
    __syncthreads();
    if (tid < 32) {
        float a = fc2b[tid];
        for (int j = 0; j < 32; j++) a += h1[j] * fc2w[tid * 32 + j];
        h2[tid] = sp_f(a);
    }
    __syncthreads();
    if (tid == 0) {
        float a = regb[0];
        for (int j = 0; j < 32; j++) a += h2[j] * regw[j];
        out[g] = a + eps[0] * sout[g];
    }
}

// ===========================================================================
extern "C" void kernel_launch(void* const* d_in, const int* in_sizes, int n_in,
                              void* d_out, int out_size, void* d_ws, size_t ws_size,
                              hipStream_t stream) {
    const float* nodes   = (const float*)d_in[0];
    const int*   es      = (const int*)d_in[1];
    const int*   et      = (const int*)d_in[2];
    const int*   gi      = (const int*)d_in[3];
    const int*   cnt     = (const int*)d_in[4];
    const int*   nsites  = (const int*)d_in[5];
    const int*   sgs     = (const int*)d_in[6];
    const float* emb_w   = (const float*)d_in[7];
    const float* emb_b   = (const float*)d_in[8];
    const float* cl_nw   = (const float*)d_in[9];
    const float* cl_ew   = (const float*)d_in[10];
    const float* cl_lw   = (const float*)d_in[11];
    const float* cl_lb   = (const float*)d_in[12];
    const float* cl_bg   = (const float*)d_in[13];
    const float* cl_bb   = (const float*)d_in[14];
    const float* se_w1   = (const float*)d_in[15];
    const float* se_b1   = (const float*)d_in[16];
    const float* se_w2   = (const float*)d_in[17];
    const float* se_b2   = (const float*)d_in[18];
    const float* se_cw   = (const float*)d_in[19];
    const float* se_cb   = (const float*)d_in[20];
    const float* se_bg   = (const float*)d_in[21];
    const float* se_bb   = (const float*)d_in[22];
    const float* sf_cw   = (const float*)d_in[23];
    const float* sf_cb   = (const float*)d_in[24];
    const float* sf_bg   = (const float*)d_in[25];
    const float* sf_bb   = (const float*)d_in[26];
    const float* ctf_w   = (const float*)d_in[27];
    const float* ctf_b   = (const float*)d_in[28];
    const float* fc1_w   = (const float*)d_in[29];
    const float* fc1_b   = (const float*)d_in[30];
    const float* fc2_w   = (const float*)d_in[31];
    const float* fc2_b   = (const float*)d_in[32];
    const float* reg_w   = (const float*)d_in[33];
    const float* reg_b   = (const float*)d_in[34];
    const float* fc3_w   = (const float*)d_in[35];
    const float* fc3_b   = (const float*)d_in[36];
    const float* eps     = (const float*)d_in[37];
    float* out = (float*)d_out;

    const size_t ATOM_B = (size_t)NN * TILE * sizeof(float);   // 33 MB
    const size_t HALO_B = (size_t)NN * ZT * sizeof(float);     // 47.2 MB
    char* ws = (char*)d_ws;
    float*  atom  = (float*)ws;              ws += ATOM_B;
    float*  An    = (float*)ws;              ws += HALO_B;
    float*  Ae    = (float*)ws;              ws += HALO_B;
    float*  outb  = (float*)ws;              ws += ATOM_B;
    double* acc   = (double*)ws;             ws += 256;
    float*  scl   = (float*)ws;              ws += 256;
    float*  shf   = (float*)ws;              ws += 256;
    float*  sout  = (float*)ws;              ws += 256;
    float*  nwT   = (float*)ws;              ws += 4608 * sizeof(float);
    float*  lwT   = (float*)ws;              ws += 4608 * sizeof(float);
    float*  crys  = (float*)ws;              ws += (size_t)BB * TILE * sizeof(float);
    float*  flat  = (float*)ws;              ws += (size_t)BB * TILE * sizeof(float);
    float*  sembp = (float*)ws;              ws += (size_t)BB * 16 * 256 * sizeof(float);
    float*  semb  = (float*)ws;              ws += (size_t)BB * 16 * 256 * sizeof(float);
    float*  ypre  = (float*)ws;              ws += (size_t)BB * 16 * 256 * sizeof(float);

    // ---- embedding
    k_embed<<<NN, 256, 0, stream>>>(nodes, emb_w, emb_b, atom);

    // ---- 3 conv layers (fp32 production path)
    for (int l = 0; l < 3; l++) {
        const float* nw = cl_nw + (size_t)l * CC * CC * 9;
        const float* ew = cl_ew + (size_t)l * CC * CC * 9;
        const float* lw = cl_lw + (size_t)l * 32 * CC * 9;
        const float* lb = cl_lb + (size_t)l * 32;
        const float* bg = cl_bg + (size_t)l * 16;
        const float* bb = cl_bb + (size_t)l * 16;

        k_wT_ne<<<18, 256, 0, stream>>>(nw, ew, nwT);
        k_wT_lin<<<18, 256, 0, stream>>>(lw, lwT);
        k_node_conv2<<<NN / 4, 256, 0, stream>>>(atom, nwT, An, Ae);
        hipMemcpyAsync(outb, atom, ATOM_B, hipMemcpyDeviceToDevice, stream);
        k_edge<<<EE / 4, 256, 0, stream>>>(An, Ae, es, et, lwT, lb, outb);
        hipMemsetAsync(acc, 0, 16 * 2 * sizeof(double), stream);
        k_bn_stats<16, 126><<<dim3(64, 16), 128, 0, stream>>>(outb, acc, NN);
        k_bn_fin<<<1, 16, 0, stream>>>(acc, bg, bb, 1.0 / ((double)NN * PP), scl, shf);
        k_bn_res<<<2048, 256, 0, stream>>>(atom, outb, scl, shf);
    }

    // ---- space branch
    k_space1<<<BB, 256, 0, stream>>>(nsites, sgs, se_w1, se_b1, se_w2, se_b2,
                                     se_cw, se_cb, sembp);
    hipMemsetAsync(acc, 0, 16 * 2 * sizeof(double), stream);
    k_bn_stats<16, 256><<<dim3(8, 16), 256, 0, stream>>>(sembp, acc, BB);
    k_bn_fin<<<1, 16, 0, stream>>>(acc, se_bg, se_bb, 1.0 / (BB * 256.0), scl, shf);
    k_bn_sp256<<<256, 256, 0, stream>>>(sembp, semb, scl, shf);
    k_space_conv<<<BB, 256, 0, stream>>>(semb, sf_cw, sf_cb, ypre);
    hipMemsetAsync(acc, 0, 16 * 2 * sizeof(double), stream);
    k_bn_stats<16, 256><<<dim3(8, 16), 256, 0, stream>>>(ypre, acc, BB);
    k_bn_fin<<<1, 16, 0, stream>>>(acc, sf_bg, sf_bb, 1.0 / (BB * 256.0), scl, shf);
    k_space_tail<<<BB, 256, 0, stream>>>(ypre, scl, shf, fc3_w, fc3_b, sout);

    // ---- pooling + conv_to_fc + head
    hipMemsetAsync(crys, 0, (size_t)BB * TILE * sizeof(float), stream);
    k_pool<<<NN, 256, 0, stream>>>(atom, gi, crys);
    k_ctf<<<BB, 256, 0, stream>>>(crys, cnt, ctf_w, ctf_b, flat);
    k_head<<<BB, 256, 0, stream>>>(flat, fc1_w, fc1_b, fc2_w, fc2_b,
                                   reg_w, reg_b, sout, eps, out);
}

// Round 14
// 1340.528 us; speedup vs baseline: 1.3435x; 1.1465x over previous
//
#include <hip/hip_runtime.h>
#include <math.h>

#define HH 7
#define WW 18
#define PP 126        // HH*WW
#define CC 16
#define NN 4096
#define EE 16384
#define BB 64
#define TILE 2016               // CC*PP, std layout
#define ZT 2880                 // 16*9*20 haloed tile (An/Ae global layout, fp32)
#define EREG 2016               // per-wave LDS region (uints): z(1440) then msg(2016 fl)

typedef _Float16 h2 __attribute__((ext_vector_type(2)));

#if __has_builtin(__builtin_amdgcn_fdot2)
#define FDOT2(a, b, c) __builtin_amdgcn_fdot2((a), (b), (c), false)
#else
#define FDOT2(a, b, c) ((float)(a)[0] * (float)(b)[0] + ((float)(a)[1] * (float)(b)[1] + (c)))
#endif

__device__ __forceinline__ h2 bch2(float f) { return __builtin_bit_cast(h2, f); }

// ---- fast transcendentals (hardware v_exp/v_log; abs err ~1e-7, thr 1.4e-3)
__device__ __forceinline__ float sp_f(float x) {
    return fmaxf(x, 0.f) + __logf(1.f + __expf(-fabsf(x)));
}
__device__ __forceinline__ float elu_f(float v) {
    return v > 0.f ? v : __expf(v) - 1.f;
}
__device__ __forceinline__ float sigm_f(float x) {
    return 1.f / (1.f + __expf(-x));
}

// ---------------- weight packs ----------------------------------------------
// node/edge dual fp32: [tap][ci][cb][4]: q=0 wN(cb), q=1 wE(cb), q=2 wN(cb+8), q=3 wE(cb+8)
__global__ void k_wT_ne(const float* __restrict__ wN, const float* __restrict__ wE,
                        float* __restrict__ wT) {
    int i = blockIdx.x * 256 + threadIdx.x;
    if (i < 4608) {
        int q = i & 3, cb = (i >> 2) & 7, ci = (i >> 5) & 15, tap = i >> 9;
        int co = cb + ((q >> 1) & 1) * 8;
        const float* src = (q & 1) ? wE : wN;
        wT[i] = src[(co * 16 + ci) * 9 + tap];
    }
}
// lin weights HALF2: [tap][cp][cb][4] of half2(ci=cp, ci=cp+8)
// q=0 filter(cb), q=1 core(cb), q=2 filter(cb+8), q=3 core(cb+8)
__global__ void k_wT_lin_h(const float* __restrict__ lw, unsigned int* __restrict__ wT) {
    int i = blockIdx.x * 256 + threadIdx.x;
    if (i < 2304) {
        int q = i & 3, cb = (i >> 2) & 7, cp = (i >> 5) & 7, tap = i >> 8;
        int co = cb + ((q >> 1) & 1) * 8 + (q & 1) * 16;
        h2 v;
        v[0] = (_Float16)lw[(co * 16 + cp) * 9 + tap];
        v[1] = (_Float16)lw[(co * 16 + cp + 8) * 9 + tap];
        wT[i] = __builtin_bit_cast(unsigned int, v);
    }
}

// ---------------- embedding -------------------------------------------------
__global__ __launch_bounds__(256) void k_embed(const float* __restrict__ nodes,
                                               const float* __restrict__ w,
                                               const float* __restrict__ b,
                                               float* __restrict__ atom) {
    __shared__ float tile[PP];
    __shared__ float ws[CC * 9];
    __shared__ float bs[CC];
    int n = blockIdx.x, tid = threadIdx.x;
    for (int i = tid; i < PP; i += 256) tile[i] = nodes[n * PP + i];
    for (int i = tid; i < CC * 9; i += 256) ws[i] = w[i];
    if (tid < CC) bs[tid] = b[tid];
    __syncthreads();
    for (int i = tid; i < CC * PP; i += 256) {
        int c = i / PP, p = i - c * PP, y = p / WW, x = p - (p / WW) * WW;
        float acc = bs[c];
#pragma unroll
        for (int dy = 0; dy < 3; dy++) {
            int yy = y + dy - 1; if ((unsigned)yy >= (unsigned)HH) continue;
#pragma unroll
            for (int dx = 0; dx < 3; dx++) {
                int xx = x + dx - 1; if ((unsigned)xx >= (unsigned)WW) continue;
                acc += tile[yy * WW + xx] * ws[c * 9 + dy * 3 + dx];
            }
        }
        atom[(size_t)n * CC * PP + i] = sp_f(acc);
    }
}

// ---------------- fp32 2-co conv core (k_node, proven R10) ------------------
__device__ __forceinline__ void conv_body4(const float* zt,
                                           const float (*ws)[16][8][4],
                                           int cb, int y,
                                           float* f0, float* c0,
                                           float* f1, float* c1) {
    for (int ci = 0; ci < 16; ci++) {
        const float* zb = zt + ci * 180 + y * 20;
#pragma unroll
        for (int dy = 0; dy < 3; dy++) {
            const float* zr = zb + dy * 20;
            float4 q0 = *(const float4*)&zr[0];
            float4 q1 = *(const float4*)&zr[4];
            float4 q2 = *(const float4*)&zr[8];
            float4 q3 = *(const float4*)&zr[12];
            float4 q4 = *(const float4*)&zr[16];
            float r[20];
            r[0]=q0.x; r[1]=q0.y; r[2]=q0.z; r[3]=q0.w;
            r[4]=q1.x; r[5]=q1.y; r[6]=q1.z; r[7]=q1.w;
            r[8]=q2.x; r[9]=q2.y; r[10]=q2.z; r[11]=q2.w;
            r[12]=q3.x; r[13]=q3.y; r[14]=q3.z; r[15]=q3.w;
            r[16]=q4.x; r[17]=q4.y; r[18]=q4.z; r[19]=q4.w;
            float4 w0 = *(const float4*)&ws[dy * 3 + 0][ci][cb][0];
            float4 w1 = *(const float4*)&ws[dy * 3 + 1][ci][cb][0];
            float4 w2 = *(const float4*)&ws[dy * 3 + 2][ci][cb][0];
#pragma unroll
            for (int x = 0; x < 18; x++) {
                f0[x] = fmaf(r[x],     w0.x, f0[x]);
                c0[x] = fmaf(r[x],     w0.y, c0[x]);
                f1[x] = fmaf(r[x],     w0.z, f1[x]);
                c1[x] = fmaf(r[x],     w0.w, c1[x]);
                f0[x] = fmaf(r[x + 1], w1.x, f0[x]);
                c0[x] = fmaf(r[x + 1], w1.y, c0[x]);
                f1[x] = fmaf(r[x + 1], w1.z, f1[x]);
                c1[x] = fmaf(r[x + 1], w1.w, c1[x]);
                f0[x] = fmaf(r[x + 2], w2.x, f0[x]);
                c0[x] = fmaf(r[x + 2], w2.y, c0[x]);
                f1[x] = fmaf(r[x + 2], w2.z, f1[x]);
                c1[x] = fmaf(r[x + 2], w2.w, c1[x]);
            }
        }
    }
}

// ------------- per-node dual conv: 1 node/WAVE (R10, fp32) ------------------
__global__ __launch_bounds__(256) void k_node_conv2(const float* __restrict__ atom,
                                                    const float* __restrict__ wT,
                                                    float* __restrict__ An,
                                                    float* __restrict__ Ae) {
    __shared__ __align__(16) float zf[4 * ZT];        // 46080 B
    __shared__ __align__(16) float ws4[9][16][8][4];  // 18432 B
    int tid = threadIdx.x;
    for (int i = tid; i < 4608; i += 256) ((float*)ws4)[i] = wT[i];
    __syncthreads();   // the only block barrier

    int we = tid >> 6, lane = tid & 63;
    int n = blockIdx.x * 4 + we;
    float* zw = &zf[we * ZT];
    const float* src = atom + (size_t)n * TILE;
    for (int r = lane; r < ZT; r += 64) {
        int ci = r / 180, rr = r - ci * 180;
        int yy = rr / 20, xx = rr - yy * 20;
        float v = 0.f;
        if ((unsigned)(yy - 1) < 7u && (unsigned)(xx - 1) < 18u)
            v = src[ci * 126 + (yy - 1) * 18 + (xx - 1)];
        zw[r] = v;
    }
    int cb = lane & 7, y = lane >> 3;
    bool act = y < 7;
    float f0[18], c0[18], f1[18], c1[18];
#pragma unroll
    for (int x = 0; x < 18; x++) { f0[x] = 0.f; c0[x] = 0.f; f1[x] = 0.f; c1[x] = 0.f; }
    if (act) conv_body4(zw, ws4, cb, y, f0, c0, f1, c1);
    for (int r = lane; r < ZT; r += 64) zw[r] = 0.f;
    int b0 = cb * 180 + (y + 1) * 20 + 1;
    int b1 = (cb + 8) * 180 + (y + 1) * 20 + 1;
    if (act) {
#pragma unroll
        for (int x = 0; x < 18; x++) { zw[b0 + x] = f0[x]; zw[b1 + x] = f1[x]; }
    }
    float4* an4 = (float4*)&An[(size_t)n * ZT];
    for (int j = lane; j < ZT / 4; j += 64) an4[j] = ((const float4*)zw)[j];
    if (act) {
#pragma unroll
        for (int x = 0; x < 18; x++) { zw[b0 + x] = c0[x]; zw[b1 + x] = c1[x]; }
    }
    float4* ae4 = (float4*)&Ae[(size_t)n * ZT];
    for (int j = lane; j < ZT / 4; j += 64) ae4[j] = ((const float4*)zw)[j];
}

// ---------------- per-edge conv: fp16 dot2, 1 edge/WAVE ---------------------
// z half2-packed along ci-pairs (c, c+8): LDS [8 cp][9 rows][20 cols] half2.
// weights half2 LDS [9 tap][8 cp][8 cb][4 q]. Accumulate fp32 via v_dot2_f32_f16.
__global__ __launch_bounds__(256) void k_edge(const float* __restrict__ An,
                                              const float* __restrict__ Ae,
                                              const int* __restrict__ es,
                                              const int* __restrict__ et,
                                              const unsigned int* __restrict__ wTh,
                                              const float* __restrict__ lb,
                                              float* __restrict__ outb) {
    __shared__ __align__(16) unsigned int zf[4 * EREG];  // 32256 B (z then msg)
    __shared__ __align__(16) unsigned int wsh[2304];     // 9216 B
    int tid = threadIdx.x;
    for (int i = tid; i < 2304; i += 256) wsh[i] = wTh[i];
    __syncthreads();   // the only block barrier

    int we = tid >> 6, lane = tid & 63;
    int e = blockIdx.x * 4 + we;
    int s = es[e], t = et[e];
    unsigned int* zw = &zf[we * EREG];
    const float4* anL = (const float4*)&An[(size_t)s * ZT];
    const float4* aeL = (const float4*)&Ae[(size_t)t * ZT];
    // load fp32 halo tiles, z = elu(an*ae), pack half2 (ci cp | ci cp+8)
    // iteration j: cp = j/45, p4 = j%45 (float4 granularity, 45 per cp-row-set)
    for (int j = lane; j < 360; j += 64) {
        int cp = j / 45, p4 = j - cp * 45;
        float4 al = anL[cp * 45 + p4];
        float4 ah = anL[(cp + 8) * 45 + p4];
        float4 bl = aeL[cp * 45 + p4];
        float4 bh = aeL[(cp + 8) * 45 + p4];
        float zl0 = elu_f(al.x * bl.x), zh0 = elu_f(ah.x * bh.x);
        float zl1 = elu_f(al.y * bl.y), zh1 = elu_f(ah.y * bh.y);
        float zl2 = elu_f(al.z * bl.z), zh2 = elu_f(ah.z * bh.z);
        float zl3 = elu_f(al.w * bl.w), zh3 = elu_f(ah.w * bh.w);
        uint4 o;
        h2 p0; p0[0] = (_Float16)zl0; p0[1] = (_Float16)zh0; o.x = __builtin_bit_cast(unsigned int, p0);
        h2 p1; p1[0] = (_Float16)zl1; p1[1] = (_Float16)zh1; o.y = __builtin_bit_cast(unsigned int, p1);
        h2 p2; p2[0] = (_Float16)zl2; p2[1] = (_Float16)zh2; o.z = __builtin_bit_cast(unsigned int, p2);
        h2 p3; p3[0] = (_Float16)zl3; p3[1] = (_Float16)zh3; o.w = __builtin_bit_cast(unsigned int, p3);
        *(uint4*)&zw[cp * 180 + p4 * 4] = o;
    }
    int cb = lane & 7, y = lane >> 3;
    bool act = y < 7;
    float f0[18], c0[18], f1[18], c1[18];
#pragma unroll
    for (int x = 0; x < 18; x++) { f0[x] = 0.f; c0[x] = 0.f; f1[x] = 0.f; c1[x] = 0.f; }
    if (act) {
        const float4* wsf4 = (const float4*)wsh;   // [tap*64 + cp*8 + cb] -> 4 half2
        for (int cp = 0; cp < 8; cp++) {
            const unsigned int* zb = zw + cp * 180 + y * 20;
#pragma unroll
            for (int dy = 0; dy < 3; dy++) {
                const float4* zr4 = (const float4*)(zb + dy * 20);
                float4 q0 = zr4[0], q1 = zr4[1], q2 = zr4[2], q3 = zr4[3], q4 = zr4[4];
                h2 r[20];
                r[0]=bch2(q0.x); r[1]=bch2(q0.y); r[2]=bch2(q0.z); r[3]=bch2(q0.w);
                r[4]=bch2(q1.x); r[5]=bch2(q1.y); r[6]=bch2(q1.z); r[7]=bch2(q1.w);
                r[8]=bch2(q2.x); r[9]=bch2(q2.y); r[10]=bch2(q2.z); r[11]=bch2(q2.w);
                r[12]=bch2(q3.x); r[13]=bch2(q3.y); r[14]=bch2(q3.z); r[15]=bch2(q3.w);
                r[16]=bch2(q4.x); r[17]=bch2(q4.y); r[18]=bch2(q4.z); r[19]=bch2(q4.w);
                float4 w0f = wsf4[(dy * 3 + 0) * 64 + cp * 8 + cb];
                float4 w1f = wsf4[(dy * 3 + 1) * 64 + cp * 8 + cb];
                float4 w2f = wsf4[(dy * 3 + 2) * 64 + cp * 8 + cb];
                h2 w0a = bch2(w0f.x), w0b = bch2(w0f.y), w0c = bch2(w0f.z), w0d = bch2(w0f.w);
                h2 w1a = bch2(w1f.x), w1b = bch2(w1f.y), w1c = bch2(w1f.z), w1d = bch2(w1f.w);
                h2 w2a = bch2(w2f.x), w2b = bch2(w2f.y), w2c = bch2(w2f.z), w2d = bch2(w2f.w);
#pragma unroll
                for (int x = 0; x < 18; x++) {
                    f0[x] = FDOT2(r[x],     w0a, f0[x]);
                    c0[x] = FDOT2(r[x],     w0b, c0[x]);
                    f1[x] = FDOT2(r[x],     w0c, f1[x]);
                    c1[x] = FDOT2(r[x],     w0d, c1[x]);
                    f0[x] = FDOT2(r[x + 1], w1a, f0[x]);
                    c0[x] = FDOT2(r[x + 1], w1b, c0[x]);
                    f1[x] = FDOT2(r[x + 1], w1c, f1[x]);
                    c1[x] = FDOT2(r[x + 1], w1d, c1[x]);
                    f0[x] = FDOT2(r[x + 2], w2a, f0[x]);
                    c0[x] = FDOT2(r[x + 2], w2b, c0[x]);
                    f1[x] = FDOT2(r[x + 2], w2c, f1[x]);
                    c1[x] = FDOT2(r[x + 2], w2d, c1[x]);
                }
            }
        }
    }
    // stage msg (fp32) in own region (z dead; wave lockstep), std layout [16ch][126]
    float* msgL = (float*)zw;
    if (act) {
        float bf0 = lb[cb], bc0 = lb[cb + 16], bf1 = lb[cb + 8], bc1 = lb[cb + 24];
        int base0 = cb * 126 + y * 18;
        int base1 = (cb + 8) * 126 + y * 18;
#pragma unroll
        for (int x = 0; x < 18; x++) {
            msgL[base0 + x] = sigm_f(f0[x] + bf0) * sp_f(c0[x] + bc0);
            msgL[base1 + x] = sigm_f(f1[x] + bf1) * sp_f(c1[x] + bc1);
        }
    }
    float* outn = outb + (size_t)s * TILE;
    for (int j = lane; j < TILE; j += 64)
        unsafeAtomicAdd(&outn[j], msgL[j]);
}

// ---------------- BN statistics (double accumulation) -----------------------
template <int C, int S>
__global__ void k_bn_stats(const float* __restrict__ X, double* __restrict__ acc, int M) {
    int c = blockIdx.y, tid = threadIdx.x;
    double s1 = 0.0, s2 = 0.0;
    for (int m = blockIdx.x; m < M; m += gridDim.x) {
        const float* xr = &X[((size_t)m * C + c) * S];
        for (int s = tid; s < S; s += blockDim.x) {
            float v = xr[s];
            s1 += v; s2 += (double)v * v;
        }
    }
    __shared__ double sh1[256], sh2[256];
    sh1[tid] = s1; sh2[tid] = s2;
    __syncthreads();
    for (int off = blockDim.x >> 1; off > 0; off >>= 1) {
        if (tid < off) { sh1[tid] += sh1[tid + off]; sh2[tid] += sh2[tid + off]; }
        __syncthreads();
    }
    if (tid == 0) {
        unsafeAtomicAdd(&acc[2 * c], sh1[0]);
        unsafeAtomicAdd(&acc[2 * c + 1], sh2[0]);
    }
}

__global__ void k_bn_fin(const double* __restrict__ acc, const float* __restrict__ g,
                         const float* __restrict__ b, double invn,
                         float* __restrict__ scl, float* __restrict__ shf) {
    int c = threadIdx.x;
    if (c < 16) {
        double m = acc[2 * c] * invn;
        double v = acc[2 * c + 1] * invn - m * m;
        double s = (double)g[c] / sqrt(v + 1e-5);
        scl[c] = (float)s;
        shf[c] = (float)((double)b[c] - s * m);
    }
}

__global__ __launch_bounds__(256) void k_bn_res(float* __restrict__ atom,
                                                const float* __restrict__ outb,
                                                const float* __restrict__ scl,
                                                const float* __restrict__ shf) {
    __shared__ float sc[16], sh[16];
    int tid = threadIdx.x;
    if (tid < 16) { sc[tid] = scl[tid]; sh[tid] = shf[tid]; }
    __syncthreads();
    const long total = (long)NN * CC * PP;
    for (long i = (long)blockIdx.x * blockDim.x + tid; i < total;
         i += (long)gridDim.x * blockDim.x) {
        int c = (int)((i / PP) & 15);
        atom[i] += sc[c] * outb[i] + sh[c];
    }
}

// ---------------- mean pooling over graphs (atomic) -------------------------
__global__ __launch_bounds__(256) void k_pool(const float* __restrict__ atom,
                                              const int* __restrict__ gi,
                                              float* __restrict__ crys) {
    int n = blockIdx.x;
    int g = gi[n];
    const float* a = &atom[(size_t)n * CC * PP];
    float* cr = &crys[(size_t)g * CC * PP];
    for (int i = threadIdx.x; i < CC * PP; i += 256) unsafeAtomicAdd(&cr[i], a[i]);
}

// ---------------- conv_to_fc ------------------------------------------------
__global__ __launch_bounds__(256) void k_ctf(const float* __restrict__ crys,
                                             const int* __restrict__ counts,
                                             const float* __restrict__ w,
                                             const float* __restrict__ b,
                                             float* __restrict__ flat) {
    __shared__ float tile[CC * PP];
    __shared__ float ws[CC * CC * 9];
    __shared__ float bs[CC];
    int g = blockIdx.x, tid = threadIdx.x;
    float cnt = (float)counts[g];
    for (int i = tid; i < CC * PP; i += 256) tile[i] = crys[(size_t)g * CC * PP + i] / cnt;
    for (int i = tid; i < CC * CC * 9; i += 256) ws[i] = w[i];
    if (tid < CC) bs[tid] = b[tid];
    __syncthreads();
    for (int i = tid; i < CC * PP; i += 256) {
        int co = i / PP, p = i - co * PP, y = p / WW, x = p - (p / WW) * WW;
        float acc = bs[co];
#pragma unroll
        for (int dy = 0; dy < 3; dy++) {
            int yy = y + dy - 1; if ((unsigned)yy >= (unsigned)HH) continue;
#pragma unroll
            for (int dx = 0; dx < 3; dx++) {
                int xx = x + dx - 1; if ((unsigned)xx >= (unsigned)WW) continue;
                int zoff = yy * WW + xx, tap = dy * 3 + dx;
                const float* tp = &tile[zoff];
                const float* wp = &ws[co * 144 + tap];
#pragma unroll
                for (int ci = 0; ci < CC; ci++) acc += tp[ci * PP] * wp[ci * 9];
            }
        }
        flat[(size_t)g * CC * PP + i] = sp_f(acc);
    }
}

// ---------------- space branch ----------------------------------------------
__global__ __launch_bounds__(256) void k_space1(const int* __restrict__ nsites,
                                                const int* __restrict__ sgs,
                                                const float* __restrict__ w1,
                                                const float* __restrict__ b1,
                                                const float* __restrict__ w2,
                                                const float* __restrict__ b2,
                                                const float* __restrict__ cw,
                                                const float* __restrict__ cb,
                                                float* __restrict__ sembp) {
    __shared__ float outer[256];
    __shared__ float row[16], col[16];
    __shared__ float cws[144], cbs[16];
    int g = blockIdx.x, tid = threadIdx.x;
    if (tid < 16) {
        float ns = (float)nsites[g], sg = (float)sgs[g];
        row[tid] = ns * w1[2 * tid] + sg * w1[2 * tid + 1] + b1[tid];
        col[tid] = ns * w2[2 * tid] + sg * w2[2 * tid + 1] + b2[tid];
        cbs[tid] = cb[tid];
    }
    if (tid >= 64 && tid < 64 + 144) cws[tid - 64] = cw[tid - 64];
    __syncthreads();
    outer[tid] = row[tid >> 4] * col[tid & 15];
    __syncthreads();
    for (int i = tid; i < 16 * 256; i += 256) {
        int c = i >> 8, p = i & 255, y = p >> 4, x = p & 15;
        float acc = cbs[c];
#pragma unroll
        for (int dy = 0; dy < 3; dy++) {
            int yy = y + dy - 1; if ((unsigned)yy >= 16u) continue;
#pragma unroll
            for (int dx = 0; dx < 3; dx++) {
                int xx = x + dx - 1; if ((unsigned)xx >= 16u) continue;
                acc += outer[yy * 16 + xx] * cws[c * 9 + dy * 3 + dx];
            }
        }
        sembp[(size_t)g * 4096 + i] = acc;
    }
}

__global__ __launch_bounds__(256) void k_bn_sp256(const float* __restrict__ X,
                                                  float* __restrict__ Y,
                                                  const float* __restrict__ scl,
                                                  const float* __restrict__ shf) {
    __shared__ float sc[16], sh[16];
    if (threadIdx.x < 16) { sc[threadIdx.x] = scl[threadIdx.x]; sh[threadIdx.x] = shf[threadIdx.x]; }
    __syncthreads();
    int total = BB * 16 * 256;
    for (int i = blockIdx.x * blockDim.x + threadIdx.x; i < total;
         i += gridDim.x * blockDim.x) {
        int c = (i >> 8) & 15;
        Y[i] = sp_f(sc[c] * X[i] + sh[c]);
    }
}

__global__ __launch_bounds__(256) void k_space_conv(const float* __restrict__ X,
                                                    const float* __restrict__ w,
                                                    const float* __restrict__ b,
                                                    float* __restrict__ Y) {
    __shared__ float tile[16 * 256];
    __shared__ float ws[2304], bs[16];
    int g = blockIdx.x, tid = threadIdx.x;
    for (int i = tid; i < 4096; i += 256) tile[i] = X[(size_t)g * 4096 + i];
    for (int i = tid; i < 2304; i += 256) ws[i] = w[i];
    if (tid < 16) bs[tid] = b[tid];
    __syncthreads();
    for (int i = tid; i < 4096; i += 256) {
        int c = i >> 8, p = i & 255, y = p >> 4, x = p & 15;
        float acc = bs[c];
#pragma unroll
        for (int dy = 0; dy < 3; dy++) {
            int yy = y + dy - 1; if ((unsigned)yy >= 16u) continue;
#pragma unroll
            for (int dx = 0; dx < 3; dx++) {
                int xx = x + dx - 1; if ((unsigned)xx >= 16u) continue;
                int tap = dy * 3 + dx;
                const float* wp = &ws[c * 144 + tap];
                const float* tp = &tile[yy * 16 + xx];
#pragma unroll
                for (int ci = 0; ci < 16; ci++) acc += tp[ci * 256] * wp[ci * 9];
            }
        }
        Y[(size_t)g * 4096 + i] = acc;
    }
}

__global__ __launch_bounds__(256) void k_space_tail(const float* __restrict__ ypre,
                                                    const float* __restrict__ scl,
                                                    const float* __restrict__ shf,
                                                    const float* __restrict__ fc3w,
                                                    const float* __restrict__ fc3b,
                                                    float* __restrict__ sout) {
    __shared__ float red[256];
    int g = blockIdx.x, tid = threadIdx.x;
    float val = 0.f;
    if (tid < 144) {
        int c = tid / 9, cell = tid - c * 9, py = cell / 3, px = cell - py * 3;
        float sc = scl[c], sh = shf[c];
        float mx = -INFINITY;
        const float* base = &ypre[((size_t)g * 16 + c) * 256];
        for (int yy = py * 5; yy < py * 5 + 5; yy++)
            for (int xx = px * 5; xx < px * 5 + 5; xx++)
                mx = fmaxf(mx, sc * base[yy * 16 + xx] + sh);
        val = sp_f(mx) * fc3w[tid];
    }
    red[tid] = val;
    __syncthreads();
    for (int off = 128; off > 0; off >>= 1) {
        if (tid < off) red[tid] += red[tid + off];
        __syncthreads();
    }
    if (tid == 0) sout[g] = red[0] + fc3b[0];
}

// ---------------- FC head ---------------------------------------------------
__global__ __launch_bounds__(256) void k_head(const float* __restrict__ flat,
                                              const float* __restrict__ fc1w,
                                              const float* __restrict__ fc1b,
                                              const float* __restrict__ fc2w,
                                              const float* __restrict__ fc2b,
                                              const float* __restrict__ regw,
                                              const float* __restrict__ regb,
                                              const float* __restrict__ sout,
                                              const float* __restrict__ eps,
                                              float* __restrict__ out) {
    int g = blockIdx.x, tid = threadIdx.x;
    __shared__ float h1[32], h2s[32];
    int o = tid >> 3, r = tid & 7;
    float part = 0.f;
    const float* fr = &flat[(size_t)g * 2016];
    const float* wr = &fc1w[(size_t)o * 2016];
    for (int j = r; j < 2016; j += 8) part += fr[j] * wr[j];
    part += __shfl_down(part, 4, 8);
    part += __shfl_down(part, 2, 8);
    part += __shfl_down(part, 1, 8);
    if (r == 0) h1[o] = sp_f(part + fc1b[o]);
    __syncthreads();
    if (tid < 32) {
        float a = fc2b[tid];
        for (int j = 0; j < 32; j++) a += h1[j] * fc2w[tid * 32 + j];
        h2s[tid] = sp_f(a);
    }
    __syncthreads();
    if (tid == 0) {
        float a = regb[0];
        for (int j = 0; j < 32; j++) a += h2s[j] * regw[j];
        out[g] = a + eps[0] * sout[g];
    }
}

// ===========================================================================
extern "C" void kernel_launch(void* const* d_in, const int* in_sizes, int n_in,
                              void* d_out, int out_size, void* d_ws, size_t ws_size,
                              hipStream_t stream) {
    const float* nodes   = (const float*)d_in[0];
    const int*   es      = (const int*)d_in[1];
    const int*   et      = (const int*)d_in[2];
    const int*   gi      = (const int*)d_in[3];
    const int*   cnt     = (const int*)d_in[4];
    const int*   nsites  = (const int*)d_in[5];
    const int*   sgs     = (const int*)d_in[6];
    const float* emb_w   = (const float*)d_in[7];
    const float* emb_b   = (const float*)d_in[8];
    const float* cl_nw   = (const float*)d_in[9];
    const float* cl_ew   = (const float*)d_in[10];
    const float* cl_lw   = (const float*)d_in[11];
    const float* cl_lb   = (const float*)d_in[12];
    const float* cl_bg   = (const float*)d_in[13];
    const float* cl_bb   = (const float*)d_in[14];
    const float* se_w1   = (const float*)d_in[15];
    const float* se_b1   = (const float*)d_in[16];
    const float* se_w2   = (const float*)d_in[17];
    const float* se_b2   = (const float*)d_in[18];
    const float* se_cw   = (const float*)d_in[19];
    const float* se_cb   = (const float*)d_in[20];
    const float* se_bg   = (const float*)d_in[21];
    const float* se_bb   = (const float*)d_in[22];
    const float* sf_cw   = (const float*)d_in[23];
    const float* sf_cb   = (const float*)d_in[24];
    const float* sf_bg   = (const float*)d_in[25];
    const float* sf_bb   = (const float*)d_in[26];
    const float* ctf_w   = (const float*)d_in[27];
    const float* ctf_b   = (const float*)d_in[28];
    const float* fc1_w   = (const float*)d_in[29];
    const float* fc1_b   = (const float*)d_in[30];
    const float* fc2_w   = (const float*)d_in[31];
    const float* fc2_b   = (const float*)d_in[32];
    const float* reg_w   = (const float*)d_in[33];
    const float* reg_b   = (const float*)d_in[34];
    const float* fc3_w   = (const float*)d_in[35];
    const float* fc3_b   = (const float*)d_in[36];
    const float* eps     = (const float*)d_in[37];
    float* out = (float*)d_out;

    const size_t ATOM_B = (size_t)NN * TILE * sizeof(float);   // 33 MB
    const size_t HALO_B = (size_t)NN * ZT * sizeof(float);     // 47.2 MB
    char* ws = (char*)d_ws;
    float*  atom  = (float*)ws;              ws += ATOM_B;
    float*  An    = (float*)ws;              ws += HALO_B;
    float*  Ae    = (float*)ws;              ws += HALO_B;
    float*  outb  = (float*)ws;              ws += ATOM_B;
    double* acc   = (double*)ws;             ws += 256;
    float*  scl   = (float*)ws;              ws += 256;
    float*  shf   = (float*)ws;              ws += 256;
    float*  sout  = (float*)ws;              ws += 256;
    float*  nwT   = (float*)ws;              ws += 4608 * sizeof(float);
    unsigned int* lwTh = (unsigned int*)ws;  ws += 2304 * sizeof(unsigned int);
    float*  crys  = (float*)ws;              ws += (size_t)BB * TILE * sizeof(float);
    float*  flat  = (float*)ws;              ws += (size_t)BB * TILE * sizeof(float);
    float*  sembp = (float*)ws;              ws += (size_t)BB * 16 * 256 * sizeof(float);
    float*  semb  = (float*)ws;              ws += (size_t)BB * 16 * 256 * sizeof(float);
    float*  ypre  = (float*)ws;              ws += (size_t)BB * 16 * 256 * sizeof(float);

    // ---- embedding
    k_embed<<<NN, 256, 0, stream>>>(nodes, emb_w, emb_b, atom);

    // ---- 3 conv layers
    for (int l = 0; l < 3; l++) {
        const float* nw = cl_nw + (size_t)l * CC * CC * 9;
        const float* ew = cl_ew + (size_t)l * CC * CC * 9;
        const float* lw = cl_lw + (size_t)l * 32 * CC * 9;
        const float* lb = cl_lb + (size_t)l * 32;
        const float* bg = cl_bg + (size_t)l * 16;
        const float* bb = cl_bb + (size_t)l * 16;

        k_wT_ne<<<18, 256, 0, stream>>>(nw, ew, nwT);
        k_wT_lin_h<<<9, 256, 0, stream>>>(lw, lwTh);
        k_node_conv2<<<NN / 4, 256, 0, stream>>>(atom, nwT, An, Ae);
        hipMemcpyAsync(outb, atom, ATOM_B, hipMemcpyDeviceToDevice, stream);
        k_edge<<<EE / 4, 256, 0, stream>>>(An, Ae, es, et, lwTh, lb, outb);
        hipMemsetAsync(acc, 0, 16 * 2 * sizeof(double), stream);
        k_bn_stats<16, 126><<<dim3(64, 16), 128, 0, stream>>>(outb, acc, NN);
        k_bn_fin<<<1, 16, 0, stream>>>(acc, bg, bb, 1.0 / ((double)NN * PP), scl, shf);
        k_bn_res<<<2048, 256, 0, stream>>>(atom, outb, scl, shf);
    }

    // ---- space branch
    k_space1<<<BB, 256, 0, stream>>>(nsites, sgs, se_w1, se_b1, se_w2, se_b2,
                                     se_cw, se_cb, sembp);
    hipMemsetAsync(acc, 0, 16 * 2 * sizeof(double), stream);
    k_bn_stats<16, 256><<<dim3(8, 16), 256, 0, stream>>>(sembp, acc, BB);
    k_bn_fin<<<1, 16, 0, stream>>>(acc, se_bg, se_bb, 1.0 / (BB * 256.0), scl, shf);
    k_bn_sp256<<<256, 256, 0, stream>>>(sembp, semb, scl, shf);
    k_space_conv<<<BB, 256, 0, stream>>>(semb, sf_cw, sf_cb, ypre);
    hipMemsetAsync(acc, 0, 16 * 2 * sizeof(double), stream);
    k_bn_stats<16, 256><<<dim3(8, 16), 256, 0, stream>>>(ypre, acc, BB);
    k_bn_fin<<<1, 16, 0, stream>>>(acc, sf_bg, sf_bb, 1.0 / (BB * 256.0), scl, shf);
    k_space_tail<<<BB, 256, 0, stream>>>(ypre, scl, shf, fc3_w, fc3_b, sout);

    // ---- pooling + conv_to_fc + head
    hipMemsetAsync(crys, 0, (size_t)BB * TILE * sizeof(float), stream);
    k_pool<<<NN, 256, 0, stream>>>(atom, gi, crys);
    k_ctf<<<BB, 256, 0, stream>>>(crys, cnt, ctf_w, ctf_b, flat);
    k_head<<<BB, 256, 0, stream>>>(flat, fc1_w, fc1_b, fc2_w, fc2_b,
                                   reg_w, reg_b, sout, eps, out);
}

// Round 15
// 1250.400 us; speedup vs baseline: 1.4403x; 1.0721x over previous
//
#include <hip/hip_runtime.h>
#include <math.h>

#define HH 7
#define WW 18
#define PP 126        // HH*WW
#define CC 16
#define NN 4096
#define EE 16384
#define BB 64
#define TILE 2016               // CC*PP, std layout
#define ZT 2880                 // 16*9*20 haloed tile (An/Ae global layout, fp32)
#define ZH 1440                 // packed half2 tile: [8 cp][9 rows][20 cols]
#define EREG 2016               // k_edge per-wave LDS region (uints): z(1440) then msg(2016 fl)

typedef _Float16 h2 __attribute__((ext_vector_type(2)));

#if __has_builtin(__builtin_amdgcn_fdot2)
#define FDOT2(a, b, c) __builtin_amdgcn_fdot2((a), (b), (c), false)
#else
#define FDOT2(a, b, c) ((float)(a)[0] * (float)(b)[0] + ((float)(a)[1] * (float)(b)[1] + (c)))
#endif

__device__ __forceinline__ h2 bch2(float f) { return __builtin_bit_cast(h2, f); }

// ---- fast transcendentals (hardware v_exp/v_log; abs err ~1e-7, thr 1.4e-3)
__device__ __forceinline__ float sp_f(float x) {
    return fmaxf(x, 0.f) + __logf(1.f + __expf(-fabsf(x)));
}
__device__ __forceinline__ float elu_f(float v) {
    return v > 0.f ? v : __expf(v) - 1.f;
}
__device__ __forceinline__ float sigm_f(float x) {
    return 1.f / (1.f + __expf(-x));
}

// ---------------- weight packs (half2 along ci-pairs) -----------------------
// lin weights: [tap][cp][cb][4] of half2(ci=cp, ci=cp+8)
// q=0 filter(cb), q=1 core(cb), q=2 filter(cb+8), q=3 core(cb+8)
__global__ void k_wT_lin_h(const float* __restrict__ lw, unsigned int* __restrict__ wT) {
    int i = blockIdx.x * 256 + threadIdx.x;
    if (i < 2304) {
        int q = i & 3, cb = (i >> 2) & 7, cp = (i >> 5) & 7, tap = i >> 8;
        int co = cb + ((q >> 1) & 1) * 8 + (q & 1) * 16;
        h2 v;
        v[0] = (_Float16)lw[(co * 16 + cp) * 9 + tap];
        v[1] = (_Float16)lw[(co * 16 + cp + 8) * 9 + tap];
        wT[i] = __builtin_bit_cast(unsigned int, v);
    }
}
// node/edge dual: q=0 wN(cb), q=1 wE(cb), q=2 wN(cb+8), q=3 wE(cb+8)
__global__ void k_wT_ne_h(const float* __restrict__ wN, const float* __restrict__ wE,
                          unsigned int* __restrict__ wT) {
    int i = blockIdx.x * 256 + threadIdx.x;
    if (i < 2304) {
        int q = i & 3, cb = (i >> 2) & 7, cp = (i >> 5) & 7, tap = i >> 8;
        int co = cb + ((q >> 1) & 1) * 8;
        const float* src = (q & 1) ? wE : wN;
        h2 v;
        v[0] = (_Float16)src[(co * 16 + cp) * 9 + tap];
        v[1] = (_Float16)src[(co * 16 + cp + 8) * 9 + tap];
        wT[i] = __builtin_bit_cast(unsigned int, v);
    }
}

// ---------------- embedding -------------------------------------------------
__global__ __launch_bounds__(256) void k_embed(const float* __restrict__ nodes,
                                               const float* __restrict__ w,
                                               const float* __restrict__ b,
                                               float* __restrict__ atom) {
    __shared__ float tile[PP];
    __shared__ float ws[CC * 9];
    __shared__ float bs[CC];
    int n = blockIdx.x, tid = threadIdx.x;
    for (int i = tid; i < PP; i += 256) tile[i] = nodes[n * PP + i];
    for (int i = tid; i < CC * 9; i += 256) ws[i] = w[i];
    if (tid < CC) bs[tid] = b[tid];
    __syncthreads();
    for (int i = tid; i < CC * PP; i += 256) {
        int c = i / PP, p = i - c * PP, y = p / WW, x = p - (p / WW) * WW;
        float acc = bs[c];
#pragma unroll
        for (int dy = 0; dy < 3; dy++) {
            int yy = y + dy - 1; if ((unsigned)yy >= (unsigned)HH) continue;
#pragma unroll
            for (int dx = 0; dx < 3; dx++) {
                int xx = x + dx - 1; if ((unsigned)xx >= (unsigned)WW) continue;
                acc += tile[yy * WW + xx] * ws[c * 9 + dy * 3 + dx];
            }
        }
        atom[(size_t)n * CC * PP + i] = sp_f(acc);
    }
}

// ---------------- shared half2 dot2 conv core -------------------------------
// zw: packed half2 tile [8 cp][9 rows][20 cols] (uints) in LDS, halos zero.
// wsh: [9 tap][8 cp][8 cb][4 q] half2 LDS. fp32 accumulate.
__device__ __forceinline__ void conv_dot2(const unsigned int* zw,
                                          const unsigned int* wsh,
                                          int cb, int y,
                                          float* f0, float* c0,
                                          float* f1, float* c1) {
    const float4* wsf4 = (const float4*)wsh;   // [tap*64 + cp*8 + cb] -> 4 half2
    for (int cp = 0; cp < 8; cp++) {
        const unsigned int* zb = zw + cp * 180 + y * 20;
#pragma unroll
        for (int dy = 0; dy < 3; dy++) {
            const float4* zr4 = (const float4*)(zb + dy * 20);
            float4 q0 = zr4[0], q1 = zr4[1], q2 = zr4[2], q3 = zr4[3], q4 = zr4[4];
            h2 r[20];
            r[0]=bch2(q0.x); r[1]=bch2(q0.y); r[2]=bch2(q0.z); r[3]=bch2(q0.w);
            r[4]=bch2(q1.x); r[5]=bch2(q1.y); r[6]=bch2(q1.z); r[7]=bch2(q1.w);
            r[8]=bch2(q2.x); r[9]=bch2(q2.y); r[10]=bch2(q2.z); r[11]=bch2(q2.w);
            r[12]=bch2(q3.x); r[13]=bch2(q3.y); r[14]=bch2(q3.z); r[15]=bch2(q3.w);
            r[16]=bch2(q4.x); r[17]=bch2(q4.y); r[18]=bch2(q4.z); r[19]=bch2(q4.w);
            float4 w0f = wsf4[(dy * 3 + 0) * 64 + cp * 8 + cb];
            float4 w1f = wsf4[(dy * 3 + 1) * 64 + cp * 8 + cb];
            float4 w2f = wsf4[(dy * 3 + 2) * 64 + cp * 8 + cb];
            h2 w0a = bch2(w0f.x), w0b = bch2(w0f.y), w0c = bch2(w0f.z), w0d = bch2(w0f.w);
            h2 w1a = bch2(w1f.x), w1b = bch2(w1f.y), w1c = bch2(w1f.z), w1d = bch2(w1f.w);
            h2 w2a = bch2(w2f.x), w2b = bch2(w2f.y), w2c = bch2(w2f.z), w2d = bch2(w2f.w);
#pragma unroll
            for (int x = 0; x < 18; x++) {
                f0[x] = FDOT2(r[x],     w0a, f0[x]);
                c0[x] = FDOT2(r[x],     w0b, c0[x]);
                f1[x] = FDOT2(r[x],     w0c, f1[x]);
                c1[x] = FDOT2(r[x],     w0d, c1[x]);
                f0[x] = FDOT2(r[x + 1], w1a, f0[x]);
                c0[x] = FDOT2(r[x + 1], w1b, c0[x]);
                f1[x] = FDOT2(r[x + 1], w1c, f1[x]);
                c1[x] = FDOT2(r[x + 1], w1d, c1[x]);
                f0[x] = FDOT2(r[x + 2], w2a, f0[x]);
                c0[x] = FDOT2(r[x + 2], w2b, c0[x]);
                f1[x] = FDOT2(r[x + 2], w2c, f1[x]);
                c1[x] = FDOT2(r[x + 2], w2d, c1[x]);
            }
        }
    }
}

// ------------- per-node dual conv: half2 dot2, 1 node/WAVE ------------------
// f0=An(cb), c0=Ae(cb), f1=An(cb+8), c1=Ae(cb+8). Outputs fp32 halo layout.
__global__ __launch_bounds__(256) void k_node_dot2(const float* __restrict__ atom,
                                                   const unsigned int* __restrict__ wTh,
                                                   float* __restrict__ An,
                                                   float* __restrict__ Ae) {
    __shared__ __align__(16) unsigned int zf[4 * ZH];   // 23040 B
    __shared__ __align__(16) unsigned int wsh[2304];    // 9216 B
    int tid = threadIdx.x;
    for (int i = tid; i < 2304; i += 256) wsh[i] = wTh[i];
    __syncthreads();   // the only block barrier

    int we = tid >> 6, lane = tid & 63;
    int n = blockIdx.x * 4 + we;
    unsigned int* zw = &zf[we * ZH];
    const float* src = atom + (size_t)n * TILE;
    // wave-private halo-gather + half2 pack (ci cp | ci cp+8), halos zero
    for (int r = lane; r < ZH; r += 64) {
        int cp = r / 180, rr = r - cp * 180;
        int yy = rr / 20, xx = rr - yy * 20;
        float v0 = 0.f, v1 = 0.f;
        if ((unsigned)(yy - 1) < 7u && (unsigned)(xx - 1) < 18u) {
            int j = (yy - 1) * 18 + (xx - 1);
            v0 = src[cp * 126 + j];
            v1 = src[(cp + 8) * 126 + j];
        }
        h2 p; p[0] = (_Float16)v0; p[1] = (_Float16)v1;
        zw[r] = __builtin_bit_cast(unsigned int, p);
    }
    int cb = lane & 7, y = lane >> 3;
    bool act = y < 7;
    float f0[18], c0[18], f1[18], c1[18];
#pragma unroll
    for (int x = 0; x < 18; x++) { f0[x] = 0.f; c0[x] = 0.f; f1[x] = 0.f; c1[x] = 0.f; }
    if (act) conv_dot2(zw, wsh, cb, y, f0, c0, f1, c1);
    // 4-chunk fp32 staging in own region (z dead; wave lockstep):
    // chunk = 1440 floats = 8 channels of halo layout
    float* st = (float*)zw;
    for (int r = lane; r < ZH; r += 64) st[r] = 0.f;
    int b0 = cb * 180 + (y + 1) * 20 + 1;
    float4* an4 = (float4*)&An[(size_t)n * ZT];
    float4* ae4 = (float4*)&Ae[(size_t)n * ZT];
    if (act) {
#pragma unroll
        for (int x = 0; x < 18; x++) st[b0 + x] = f0[x];
    }
    for (int j = lane; j < ZH / 4; j += 64) an4[j] = ((const float4*)st)[j];
    if (act) {
#pragma unroll
        for (int x = 0; x < 18; x++) st[b0 + x] = f1[x];
    }
    for (int j = lane; j < ZH / 4; j += 64) an4[ZH / 4 + j] = ((const float4*)st)[j];
    if (act) {
#pragma unroll
        for (int x = 0; x < 18; x++) st[b0 + x] = c0[x];
    }
    for (int j = lane; j < ZH / 4; j += 64) ae4[j] = ((const float4*)st)[j];
    if (act) {
#pragma unroll
        for (int x = 0; x < 18; x++) st[b0 + x] = c1[x];
    }
    for (int j = lane; j < ZH / 4; j += 64) ae4[ZH / 4 + j] = ((const float4*)st)[j];
}

// ---------------- per-edge conv: fp16 dot2, 1 edge/WAVE (R14, proven) -------
__global__ __launch_bounds__(256) void k_edge(const float* __restrict__ An,
                                              const float* __restrict__ Ae,
                                              const int* __restrict__ es,
                                              const int* __restrict__ et,
                                              const unsigned int* __restrict__ wTh,
                                              const float* __restrict__ lb,
                                              float* __restrict__ outb) {
    __shared__ __align__(16) unsigned int zf[4 * EREG];  // 32256 B (z then msg)
    __shared__ __align__(16) unsigned int wsh[2304];     // 9216 B
    int tid = threadIdx.x;
    for (int i = tid; i < 2304; i += 256) wsh[i] = wTh[i];
    __syncthreads();   // the only block barrier

    int we = tid >> 6, lane = tid & 63;
    int e = blockIdx.x * 4 + we;
    int s = es[e], t = et[e];
    unsigned int* zw = &zf[we * EREG];
    const float4* anL = (const float4*)&An[(size_t)s * ZT];
    const float4* aeL = (const float4*)&Ae[(size_t)t * ZT];
    for (int j = lane; j < 360; j += 64) {
        int cp = j / 45, p4 = j - cp * 45;
        float4 al = anL[cp * 45 + p4];
        float4 ah = anL[(cp + 8) * 45 + p4];
        float4 bl = aeL[cp * 45 + p4];
        float4 bh = aeL[(cp + 8) * 45 + p4];
        float zl0 = elu_f(al.x * bl.x), zh0 = elu_f(ah.x * bh.x);
        float zl1 = elu_f(al.y * bl.y), zh1 = elu_f(ah.y * bh.y);
        float zl2 = elu_f(al.z * bl.z), zh2 = elu_f(ah.z * bh.z);
        float zl3 = elu_f(al.w * bl.w), zh3 = elu_f(ah.w * bh.w);
        uint4 o;
        h2 p0; p0[0] = (_Float16)zl0; p0[1] = (_Float16)zh0; o.x = __builtin_bit_cast(unsigned int, p0);
        h2 p1; p1[0] = (_Float16)zl1; p1[1] = (_Float16)zh1; o.y = __builtin_bit_cast(unsigned int, p1);
        h2 p2; p2[0] = (_Float16)zl2; p2[1] = (_Float16)zh2; o.z = __builtin_bit_cast(unsigned int, p2);
        h2 p3; p3[0] = (_Float16)zl3; p3[1] = (_Float16)zh3; o.w = __builtin_bit_cast(unsigned int, p3);
        *(uint4*)&zw[cp * 180 + p4 * 4] = o;
    }
    int cb = lane & 7, y = lane >> 3;
    bool act = y < 7;
    float f0[18], c0[18], f1[18], c1[18];
#pragma unroll
    for (int x = 0; x < 18; x++) { f0[x] = 0.f; c0[x] = 0.f; f1[x] = 0.f; c1[x] = 0.f; }
    if (act) conv_dot2(zw, wsh, cb, y, f0, c0, f1, c1);
    float* msgL = (float*)zw;
    if (act) {
        float bf0 = lb[cb], bc0 = lb[cb + 16], bf1 = lb[cb + 8], bc1 = lb[cb + 24];
        int base0 = cb * 126 + y * 18;
        int base1 = (cb + 8) * 126 + y * 18;
#pragma unroll
        for (int x = 0; x < 18; x++) {
            msgL[base0 + x] = sigm_f(f0[x] + bf0) * sp_f(c0[x] + bc0);
            msgL[base1 + x] = sigm_f(f1[x] + bf1) * sp_f(c1[x] + bc1);
        }
    }
    float* outn = outb + (size_t)s * TILE;
    for (int j = lane; j < TILE; j += 64)
        unsafeAtomicAdd(&outn[j], msgL[j]);
}

// ---------------- BN statistics (double accumulation) -----------------------
template <int C, int S>
__global__ void k_bn_stats(const float* __restrict__ X, double* __restrict__ acc, int M) {
    int c = blockIdx.y, tid = threadIdx.x;
    double s1 = 0.0, s2 = 0.0;
    for (int m = blockIdx.x; m < M; m += gridDim.x) {
        const float* xr = &X[((size_t)m * C + c) * S];
        for (int s = tid; s < S; s += blockDim.x) {
            float v = xr[s];
            s1 += v; s2 += (double)v * v;
        }
    }
    __shared__ double sh1[256], sh2[256];
    sh1[tid] = s1; sh2[tid] = s2;
    __syncthreads();
    for (int off = blockDim.x >> 1; off > 0; off >>= 1) {
        if (tid < off) { sh1[tid] += sh1[tid + off]; sh2[tid] += sh2[tid + off]; }
        __syncthreads();
    }
    if (tid == 0) {
        unsafeAtomicAdd(&acc[2 * c], sh1[0]);
        unsafeAtomicAdd(&acc[2 * c + 1], sh2[0]);
    }
}

__global__ void k_bn_fin(const double* __restrict__ acc, const float* __restrict__ g,
                         const float* __restrict__ b, double invn,
                         float* __restrict__ scl, float* __restrict__ shf) {
    int c = threadIdx.x;
    if (c < 16) {
        double m = acc[2 * c] * invn;
        double v = acc[2 * c + 1] * invn - m * m;
        double s = (double)g[c] / sqrt(v + 1e-5);
        scl[c] = (float)s;
        shf[c] = (float)((double)b[c] - s * m);
    }
}

__global__ __launch_bounds__(256) void k_bn_res(float* __restrict__ atom,
                                                const float* __restrict__ outb,
                                                const float* __restrict__ scl,
                                                const float* __restrict__ shf) {
    __shared__ float sc[16], sh[16];
    int tid = threadIdx.x;
    if (tid < 16) { sc[tid] = scl[tid]; sh[tid] = shf[tid]; }
    __syncthreads();
    const long total = (long)NN * CC * PP;
    for (long i = (long)blockIdx.x * blockDim.x + tid; i < total;
         i += (long)gridDim.x * blockDim.x) {
        int c = (int)((i / PP) & 15);
        atom[i] += sc[c] * outb[i] + sh[c];
    }
}

// ---------------- mean pooling over graphs (atomic) -------------------------
__global__ __launch_bounds__(256) void k_pool(const float* __restrict__ atom,
                                              const int* __restrict__ gi,
                                              float* __restrict__ crys) {
    int n = blockIdx.x;
    int g = gi[n];
    const float* a = &atom[(size_t)n * CC * PP];
    float* cr = &crys[(size_t)g * CC * PP];
    for (int i = threadIdx.x; i < CC * PP; i += 256) unsafeAtomicAdd(&cr[i], a[i]);
}

// ---------------- conv_to_fc ------------------------------------------------
__global__ __launch_bounds__(256) void k_ctf(const float* __restrict__ crys,
                                             const int* __restrict__ counts,
                                             const float* __restrict__ w,
                                             const float* __restrict__ b,
                                             float* __restrict__ flat) {
    __shared__ float tile[CC * PP];
    __shared__ float ws[CC * CC * 9];
    __shared__ float bs[CC];
    int g = blockIdx.x, tid = threadIdx.x;
    float cnt = (float)counts[g];
    for (int i = tid; i < CC * PP; i += 256) tile[i] = crys[(size_t)g * CC * PP + i] / cnt;
    for (int i = tid; i < CC * CC * 9; i += 256) ws[i] = w[i];
    if (tid < CC) bs[tid] = b[tid];
    __syncthreads();
    for (int i = tid; i < CC * PP; i += 256) {
        int co = i / PP, p = i - co * PP, y = p / WW, x = p - (p / WW) * WW;
        float acc = bs[co];
#pragma unroll
        for (int dy = 0; dy < 3; dy++) {
            int yy = y + dy - 1; if ((unsigned)yy >= (unsigned)HH) continue;
#pragma unroll
            for (int dx = 0; dx < 3; dx++) {
                int xx = x + dx - 1; if ((unsigned)xx >= (unsigned)WW) continue;
                int zoff = yy * WW + xx, tap = dy * 3 + dx;
                const float* tp = &tile[zoff];
                const float* wp = &ws[co * 144 + tap];
#pragma unroll
                for (int ci = 0; ci < CC; ci++) acc += tp[ci * PP] * wp[ci * 9];
            }
        }
        flat[(size_t)g * CC * PP + i] = sp_f(acc);
    }
}

// ---------------- space branch ----------------------------------------------
__global__ __launch_bounds__(256) void k_space1(const int* __restrict__ nsites,
                                                const int* __restrict__ sgs,
                                                const float* __restrict__ w1,
                                                const float* __restrict__ b1,
                                                const float* __restrict__ w2,
                                                const float* __restrict__ b2,
                                                const float* __restrict__ cw,
                                                const float* __restrict__ cb,
                                                float* __restrict__ sembp) {
    __shared__ float outer[256];
    __shared__ float row[16], col[16];
    __shared__ float cws[144], cbs[16];
    int g = blockIdx.x, tid = threadIdx.x;
    if (tid < 16) {
        float ns = (float)nsites[g], sg = (float)sgs[g];
        row[tid] = ns * w1[2 * tid] + sg * w1[2 * tid + 1] + b1[tid];
        col[tid] = ns * w2[2 * tid] + sg * w2[2 * tid + 1] + b2[tid];
        cbs[tid] = cb[tid];
    }
    if (tid >= 64 && tid < 64 + 144) cws[tid - 64] = cw[tid - 64];
    __syncthreads();
    outer[tid] = row[tid >> 4] * col[tid & 15];
    __syncthreads();
    for (int i = tid; i < 16 * 256; i += 256) {
        int c = i >> 8, p = i & 255, y = p >> 4, x = p & 15;
        float acc = cbs[c];
#pragma unroll
        for (int dy = 0; dy < 3; dy++) {
            int yy = y + dy - 1; if ((unsigned)yy >= 16u) continue;
#pragma unroll
            for (int dx = 0; dx < 3; dx++) {
                int xx = x + dx - 1; if ((unsigned)xx >= 16u) continue;
                acc += outer[yy * 16 + xx] * cws[c * 9 + dy * 3 + dx];
            }
        }
        sembp[(size_t)g * 4096 + i] = acc;
    }
}

__global__ __launch_bounds__(256) void k_bn_sp256(const float* __restrict__ X,
                                                  float* __restrict__ Y,
                                                  const float* __restrict__ scl,
                                                  const float* __restrict__ shf) {
    __shared__ float sc[16], sh[16];
    if (threadIdx.x < 16) { sc[threadIdx.x] = scl[threadIdx.x]; sh[threadIdx.x] = shf[threadIdx.x]; }
    __syncthreads();
    int total = BB * 16 * 256;
    for (int i = blockIdx.x * blockDim.x + threadIdx.x; i < total;
         i += gridDim.x * blockDim.x) {
        int c = (i >> 8) & 15;
        Y[i] = sp_f(sc[c] * X[i] + sh[c]);
    }
}

__global__ __launch_bounds__(256) void k_space_conv(const float* __restrict__ X,
                                                    const float* __restrict__ w,
                                                    const float* __restrict__ b,
                                                    float* __restrict__ Y) {
    __shared__ float tile[16 * 256];
    __shared__ float ws[2304], bs[16];
    int g = blockIdx.x, tid = threadIdx.x;
    for (int i = tid; i < 4096; i += 256) tile[i] = X[(size_t)g * 4096 + i];
    for (int i = tid; i < 2304; i += 256) ws[i] = w[i];
    if (tid < 16) bs[tid] = b[tid];
    __syncthreads();
    for (int i = tid; i < 4096; i += 256) {
        int c = i >> 8, p = i & 255, y = p >> 4, x = p & 15;
        float acc = bs[c];
#pragma unroll
        for (int dy = 0; dy < 3; dy++) {
            int yy = y + dy - 1; if ((unsigned)yy >= 16u) continue;
#pragma unroll
            for (int dx = 0; dx < 3; dx++) {
                int xx = x + dx - 1; if ((unsigned)xx >= 16u) continue;
                int tap = dy * 3 + dx;
                const float* wp = &ws[c * 144 + tap];
                const float* tp = &tile[yy * 16 + xx];
#pragma unroll
                for (int ci = 0; ci < 16; ci++) acc += tp[ci * 256] * wp[ci * 9];
            }
        }
        Y[(size_t)g * 4096 + i] = acc;
    }
}

__global__ __launch_bounds__(256) void k_space_tail(const float* __restrict__ ypre,
                                                    const float* __restrict__ scl,
                                                    const float* __restrict__ shf,
                                                    const float* __restrict__ fc3w,
                                                    const float* __restrict__ fc3b,
                                                    float* __restrict__ sout) {
    __shared__ float red[256];
    int g = blockIdx.x, tid = threadIdx.x;
    float val = 0.f;
    if (tid < 144) {
        int c = tid / 9, cell = tid - c * 9, py = cell / 3, px = cell - py * 3;
        float sc = scl[c], sh = shf[c];
        float mx = -INFINITY;
        const float* base = &ypre[((size_t)g * 16 + c) * 256];
        for (int yy = py * 5; yy < py * 5 + 5; yy++)
            for (int xx = px * 5; xx < px * 5 + 5; xx++)
                mx = fmaxf(mx, sc * base[yy * 16 + xx] + sh);
        val = sp_f(mx) * fc3w[tid];
    }
    red[tid] = val;
    __syncthreads();
    for (int off = 128; off > 0; off >>= 1) {
        if (tid < off) red[tid] += red[tid + off];
        __syncthreads();
    }
    if (tid == 0) sout[g] = red[0] + fc3b[0];
}

// ---------------- FC head ---------------------------------------------------
__global__ __launch_bounds__(256) void k_head(const float* __restrict__ flat,
                                              const float* __restrict__ fc1w,
                                              const float* __restrict__ fc1b,
                                              const float* __restrict__ fc2w,
                                              const float* __restrict__ fc2b,
                                              const float* __restrict__ regw,
                                              const float* __restrict__ regb,
                                              const float* __restrict__ sout,
                                              const float* __restrict__ eps,
                                              float* __restrict__ out) {
    int g = blockIdx.x, tid = threadIdx.x;
    __shared__ float h1[32], h2s[32];
    int o = tid >> 3, r = tid & 7;
    float part = 0.f;
    const float* fr = &flat[(size_t)g * 2016];
    const float* wr = &fc1w[(size_t)o * 2016];
    for (int j = r; j < 2016; j += 8) part += fr[j] * wr[j];
    part += __shfl_down(part, 4, 8);
    part += __shfl_down(part, 2, 8);
    part += __shfl_down(part, 1, 8);
    if (r == 0) h1[o] = sp_f(part + fc1b[o]);
    __syncthreads();
    if (tid < 32) {
        float a = fc2b[tid];
        for (int j = 0; j < 32; j++) a += h1[j] * fc2w[tid * 32 + j];
        h2s[tid] = sp_f(a);
    }
    __syncthreads();
    if (tid == 0) {
        float a = regb[0];
        for (int j = 0; j < 32; j++) a += h2s[j] * regw[j];
        out[g] = a + eps[0] * sout[g];
    }
}

// ===========================================================================
extern "C" void kernel_launch(void* const* d_in, const int* in_sizes, int n_in,
                              void* d_out, int out_size, void* d_ws, size_t ws_size,
                              hipStream_t stream) {
    const float* nodes   = (const float*)d_in[0];
    const int*   es      = (const int*)d_in[1];
    const int*   et      = (const int*)d_in[2];
    const int*   gi      = (const int*)d_in[3];
    const int*   cnt     = (const int*)d_in[4];
    const int*   nsites  = (const int*)d_in[5];
    const int*   sgs     = (const int*)d_in[6];
    const float* emb_w   = (const float*)d_in[7];
    const float* emb_b   = (const float*)d_in[8];
    const float* cl_nw   = (const float*)d_in[9];
    const float* cl_ew   = (const float*)d_in[10];
    const float* cl_lw   = (const float*)d_in[11];
    const float* cl_lb   = (const float*)d_in[12];
    const float* cl_bg   = (const float*)d_in[13];
    const float* cl_bb   = (const float*)d_in[14];
    const float* se_w1   = (const float*)d_in[15];
    const float* se_b1   = (const float*)d_in[16];
    const float* se_w2   = (const float*)d_in[17];
    const float* se_b2   = (const float*)d_in[18];
    const float* se_cw   = (const float*)d_in[19];
    const float* se_cb   = (const float*)d_in[20];
    const float* se_bg   = (const float*)d_in[21];
    const float* se_bb   = (const float*)d_in[22];
    const float* sf_cw   = (const float*)d_in[23];
    const float* sf_cb   = (const float*)d_in[24];
    const float* sf_bg   = (const float*)d_in[25];
    const float* sf_bb   = (const float*)d_in[26];
    const float* ctf_w   = (const float*)d_in[27];
    const float* ctf_b   = (const float*)d_in[28];
    const float* fc1_w   = (const float*)d_in[29];
    const float* fc1_b   = (const float*)d_in[30];
    const float* fc2_w   = (const float*)d_in[31];
    const float* fc2_b   = (const float*)d_in[32];
    const float* reg_w   = (const float*)d_in[33];
    const float* reg_b   = (const float*)d_in[34];
    const float* fc3_w   = (const float*)d_in[35];
    const float* fc3_b   = (const float*)d_in[36];
    const float* eps     = (const float*)d_in[37];
    float* out = (float*)d_out;

    const size_t ATOM_B = (size_t)NN * TILE * sizeof(float);   // 33 MB
    const size_t HALO_B = (size_t)NN * ZT * sizeof(float);     // 47.2 MB
    char* ws = (char*)d_ws;
    float*  atom  = (float*)ws;              ws += ATOM_B;
    float*  An    = (float*)ws;              ws += HALO_B;
    float*  Ae    = (float*)ws;              ws += HALO_B;
    float*  outb  = (float*)ws;              ws += ATOM_B;
    double* acc   = (double*)ws;             ws += 256;
    float*  scl   = (float*)ws;              ws += 256;
    float*  shf   = (float*)ws;              ws += 256;
    float*  sout  = (float*)ws;              ws += 256;
    unsigned int* nwTh = (unsigned int*)ws;  ws += 2304 * sizeof(unsigned int);
    unsigned int* lwTh = (unsigned int*)ws;  ws += 2304 * sizeof(unsigned int);
    float*  crys  = (float*)ws;              ws += (size_t)BB * TILE * sizeof(float);
    float*  flat  = (float*)ws;              ws += (size_t)BB * TILE * sizeof(float);
    float*  sembp = (float*)ws;              ws += (size_t)BB * 16 * 256 * sizeof(float);
    float*  semb  = (float*)ws;              ws += (size_t)BB * 16 * 256 * sizeof(float);
    float*  ypre  = (float*)ws;              ws += (size_t)BB * 16 * 256 * sizeof(float);

    // ---- embedding
    k_embed<<<NN, 256, 0, stream>>>(nodes, emb_w, emb_b, atom);

    // ---- 3 conv layers
    for (int l = 0; l < 3; l++) {
        const float* nw = cl_nw + (size_t)l * CC * CC * 9;
        const float* ew = cl_ew + (size_t)l * CC * CC * 9;
        const float* lw = cl_lw + (size_t)l * 32 * CC * 9;
        const float* lb = cl_lb + (size_t)l * 32;
        const float* bg = cl_bg + (size_t)l * 16;
        const float* bb = cl_bb + (size_t)l * 16;

        k_wT_ne_h<<<9, 256, 0, stream>>>(nw, ew, nwTh);
        k_wT_lin_h<<<9, 256, 0, stream>>>(lw, lwTh);
        k_node_dot2<<<NN / 4, 256, 0, stream>>>(atom, nwTh, An, Ae);
        hipMemcpyAsync(outb, atom, ATOM_B, hipMemcpyDeviceToDevice, stream);
        k_edge<<<EE / 4, 256, 0, stream>>>(An, Ae, es, et, lwTh, lb, outb);
        hipMemsetAsync(acc, 0, 16 * 2 * sizeof(double), stream);
        k_bn_stats<16, 126><<<dim3(64, 16), 128, 0, stream>>>(outb, acc, NN);
        k_bn_fin<<<1, 16, 0, stream>>>(acc, bg, bb, 1.0 / ((double)NN * PP), scl, shf);
        k_bn_res<<<2048, 256, 0, stream>>>(atom, outb, scl, shf);
    }

    // ---- space branch
    k_space1<<<BB, 256, 0, stream>>>(nsites, sgs, se_w1, se_b1, se_w2, se_b2,
                                     se_cw, se_cb, sembp);
    hipMemsetAsync(acc, 0, 16 * 2 * sizeof(double), stream);
    k_bn_stats<16, 256><<<dim3(8, 16), 256, 0, stream>>>(sembp, acc, BB);
    k_bn_fin<<<1, 16, 0, stream>>>(acc, se_bg, se_bb, 1.0 / (BB * 256.0), scl, shf);
    k_bn_sp256<<<256, 256, 0, stream>>>(sembp, semb, scl, shf);
    k_space_conv<<<BB, 256, 0, stream>>>(semb, sf_cw, sf_cb, ypre);
    hipMemsetAsync(acc, 0, 16 * 2 * sizeof(double), stream);
    k_bn_stats<16, 256><<<dim3(8, 16), 256, 0, stream>>>(ypre, acc, BB);
    k_bn_fin<<<1, 16, 0, stream>>>(acc, sf_bg, sf_bb, 1.0 / (BB * 256.0), scl, shf);
    k_space_tail<<<BB, 256, 0, stream>>>(ypre, scl, shf, fc3_w, fc3_b, sout);

    // ---- pooling + conv_to_fc + head
    hipMemsetAsync(crys, 0, (size_t)BB * TILE * sizeof(float), stream);
    k_pool<<<NN, 256, 0, stream>>>(atom, gi, crys);
    k_ctf<<<BB, 256, 0, stream>>>(crys, cnt, ctf_w, ctf_b, flat);
    k_head<<<BB, 256, 0, stream>>>(flat, fc1_w, fc1_b, fc2_w, fc2_b,
                                   reg_w, reg_b, sout, eps, out);
}